// Round 6
// baseline (616.789 us; speedup 1.0000x reference)
//
#include <hip/hip_runtime.h>

// (B,S,D,K,F) = (4, 2048, 1024, 4, 4096)
static constexpr int Bb = 4;
static constexpr int Ss = 2048;
static constexpr int Dd = 1024;
static constexpr int Ff = 4096;
static constexpr int Mm = Bb * Ss;              // 8192 rows
static constexpr size_t ND = (size_t)Mm * Dd;   // 8388608
static constexpr int CH = 32;                   // scan chunks
static constexpr int CL = Ss / CH;              // chunk length 64

typedef __attribute__((ext_vector_type(8))) short short8;
typedef __attribute__((ext_vector_type(4))) float floatx4;

__device__ __forceinline__ unsigned f2bf(float f) {
  unsigned u = __builtin_bit_cast(unsigned, f);
  return (u + 0x7FFFu + ((u >> 16) & 1u)) >> 16;   // RNE
}
__device__ __forceinline__ float bf2f(unsigned bits) {
  return __builtin_bit_cast(float, bits << 16);
}
__device__ __forceinline__ void gload_lds16(const void* g, void* lds) {
  __builtin_amdgcn_global_load_lds((const __attribute__((address_space(1))) void*)g,
                                   (__attribute__((address_space(3))) void*)lds,
                                   16, 0, 0);
}
// fast sigmoid / tanh-gelu via hw v_exp_f32 + v_rcp_f32 (f32-accurate ~1e-6)
__device__ __forceinline__ float fsig(float x) {
  return __builtin_amdgcn_rcpf(1.0f + __expf(-x));
}
__device__ __forceinline__ float fgelu(float v) {
  float z = 1.5957691216057308f * fmaf(0.044715f * v, v * v, v);
  return v * __builtin_amdgcn_rcpf(1.0f + __expf(-z));
}

// ---------------- weight transpose + fp32->bf16: W[K][N] -> WT[N][K] --------
__global__ __launch_bounds__(256) void wconv_k(const float* __restrict__ W,
                                               unsigned short* __restrict__ WT,
                                               int K, int N) {
  __shared__ float tile[32][33];
  int tx = threadIdx.x & 31, ty = threadIdx.x >> 5;
  int bx = blockIdx.x * 32, by = blockIdx.y * 32;
#pragma unroll
  for (int i = 0; i < 32; i += 8)
    tile[ty + i][tx] = W[(size_t)(by + ty + i) * N + bx + tx];
  __syncthreads();
#pragma unroll
  for (int i = 0; i < 32; i += 8)
    WT[(size_t)(bx + ty + i) * K + by + tx] = (unsigned short)f2bf(tile[tx][ty + i]);
}

// ---------------- RMSNorm: fp32 in, bf16 out --------------------------------
__global__ __launch_bounds__(256) void rmsnorm_bf_k(const float* __restrict__ x,
                                                    const float* __restrict__ w,
                                                    unsigned short* __restrict__ out) {
  int row = blockIdx.x;
  const float4* xr = (const float4*)(x + (size_t)row * Dd);
  int t = threadIdx.x;
  float4 v = xr[t];
  float ss = v.x * v.x + v.y * v.y + v.z * v.z + v.w * v.w;
#pragma unroll
  for (int off = 32; off > 0; off >>= 1) ss += __shfl_down(ss, off, 64);
  __shared__ float sb[4];
  if ((t & 63) == 0) sb[t >> 6] = ss;
  __syncthreads();
  float tot = sb[0] + sb[1] + sb[2] + sb[3];
  float sc = rsqrtf(tot * (1.0f / (float)Dd) + 1e-6f);
  float4 wv = ((const float4*)w)[t];
  unsigned lo = f2bf(v.x * sc * wv.x) | (f2bf(v.y * sc * wv.y) << 16);
  unsigned hi = f2bf(v.z * sc * wv.z) | (f2bf(v.w * sc * wv.w) << 16);
  *(uint2*)(out + (size_t)row * Dd + t * 4) = make_uint2(lo, hi);
}

// ---------------- Causal depthwise conv (bf16 in/out) -> concat[:,0:D] ------
__global__ __launch_bounds__(256) void conv_k(const unsigned short* __restrict__ xn,
                                              const float* __restrict__ kern,
                                              const float* __restrict__ bias,
                                              unsigned short* __restrict__ outC) {
  size_t q = (size_t)blockIdx.x * 256 + threadIdx.x;  // over ND/4
  size_t i = q * 4;
  int d = (int)(i & (Dd - 1));
  int m = (int)(i >> 10);
  int t = m & (Ss - 1);
  float acc[4];
#pragma unroll
  for (int j = 0; j < 4; j++) acc[j] = bias[d + j];
#pragma unroll
  for (int k = 0; k < 4; k++) {
    if (t >= k) {
      uint2 xv = *(const uint2*)(xn + i - (size_t)k * Dd);
      float x0 = bf2f(xv.x & 0xFFFF), x1 = bf2f(xv.x >> 16);
      float x2 = bf2f(xv.y & 0xFFFF), x3 = bf2f(xv.y >> 16);
      acc[0] = fmaf(kern[(d + 0) * 4 + k], x0, acc[0]);
      acc[1] = fmaf(kern[(d + 1) * 4 + k], x1, acc[1]);
      acc[2] = fmaf(kern[(d + 2) * 4 + k], x2, acc[2]);
      acc[3] = fmaf(kern[(d + 3) * 4 + k], x3, acc[3]);
    }
  }
  unsigned lo = f2bf(acc[0]) | (f2bf(acc[1]) << 16);
  unsigned hi = f2bf(acc[2]) | (f2bf(acc[3]) << 16);
  *(uint2*)(outC + (size_t)m * (2 * Dd) + d) = make_uint2(lo, hi);
}

// ---------------- bf16 MFMA GEMM v4: m201-style 8-phase 256x256 template ----
// (unchanged -- measured r4/r5: FETCH collapse, 0 bank conflicts, VGPR=128)
// MODE bits: 1=+bias[col], 2=gelu, 4=+extra (fp32), 8=bf16 out, 16=velocity
template <int MODE>
__global__ __launch_bounds__(512, 2) void bgemm3_k(const unsigned short* __restrict__ A,
                                                   const unsigned short* __restrict__ BT,
                                                   void* __restrict__ Cout,
                                                   int M, int N, int K,
                                                   const float* __restrict__ bias,
                                                   const float* __restrict__ extra,
                                                   const float* __restrict__ vel_in,
                                                   const float* __restrict__ x_in,
                                                   const float* __restrict__ log_beta,
                                                   float* __restrict__ vel_out) {
  __shared__ unsigned short LA[2][256 * 64];   // 64 KiB
  __shared__ unsigned short LB[2][256 * 64];   // 64 KiB
  const int tid = threadIdx.x;
  const int wid = tid >> 6, lane = tid & 63;
  const int wm = wid >> 2, wn = wid & 3;       // 2M x 4N wave grid
  const int r = lane & 15, quad = lane >> 4, r7 = lane & 7;

  const int gx = gridDim.x;
  int id = blockIdx.y * gx + blockIdx.x;
  const int nwg = gx * gridDim.y;
  id = (id & 7) * (nwg >> 3) + (id >> 3);
  const int bm = (id / gx) * 256, bn = (id % gx) * 256;
  const int NIT = K >> 7;                      // iterations of 2 K-tiles

  const int lrow = lane >> 3;
  const int sblk = (lane & 7) ^ lrow;          // pre-swizzled 16B block index
  const unsigned short* AsrcB = A  + (size_t)(bm + lrow) * K + sblk * 8;
  const unsigned short* BsrcB = BT + (size_t)(bn + lrow) * K + sblk * 8;

  const int aB = wm * 8192 + r * 64;
  const int bB = wn * 4096 + r * 64;
  const int kq0 = (quad ^ r7) * 8;
  const int kq1 = ((4 + quad) ^ r7) * 8;

  floatx4 acc[8][4];
#pragma unroll
  for (int i = 0; i < 8; i++)
#pragma unroll
    for (int j = 0; j < 4; j++) acc[i][j] = (floatx4){0.f, 0.f, 0.f, 0.f};

#define STG_A(bq, k0, h, s)                                                           \
  gload_lds16(AsrcB + (size_t)((h) * 128 + (s) * 64 + wid * 8) * K + (k0),            \
              (void*)&LA[bq][((h) * 128 + (s) * 64 + wid * 8) * 64])
#define STG_B(bq, k0, h, s)                                                           \
  gload_lds16(BsrcB + (size_t)((h) * 128 + (s) * 64 + wid * 8) * K + (k0),            \
              (void*)&LB[bq][((h) * 128 + (s) * 64 + wid * 8) * 64])
#define RDA(il, IH, buf)                                                              \
  aF[il][0] = *(const short8*)&LA[buf][aB + (IH) * 4096 + (il) * 1024 + kq0];         \
  aF[il][1] = *(const short8*)&LA[buf][aB + (IH) * 4096 + (il) * 1024 + kq1]
#define RDB(BF, jl, jg, buf)                                                          \
  BF[jl][0] = *(const short8*)&LB[buf][bB + (jg) * 1024 + kq0];                       \
  BF[jl][1] = *(const short8*)&LB[buf][bB + (jg) * 1024 + kq1]
#define MM2(il, jl, BF, IH, JH)                                                       \
  acc[(IH) * 4 + (il)][(JH) * 2 + (jl)] = __builtin_amdgcn_mfma_f32_16x16x32_bf16(    \
      BF[jl][0], aF[il][0], acc[(IH) * 4 + (il)][(JH) * 2 + (jl)], 0, 0, 0);          \
  acc[(IH) * 4 + (il)][(JH) * 2 + (jl)] = __builtin_amdgcn_mfma_f32_16x16x32_bf16(    \
      BF[jl][1], aF[il][1], acc[(IH) * 4 + (il)][(JH) * 2 + (jl)], 0, 0, 0)
#define MQUAD(BF, IH, JH)                                                             \
  MM2(0, 0, BF, IH, JH); MM2(0, 1, BF, IH, JH); MM2(1, 0, BF, IH, JH);                \
  MM2(1, 1, BF, IH, JH); MM2(2, 0, BF, IH, JH); MM2(2, 1, BF, IH, JH);                \
  MM2(3, 0, BF, IH, JH); MM2(3, 1, BF, IH, JH)
#define BAR() __builtin_amdgcn_s_barrier()
#define LGK0()                                                                        \
  asm volatile("s_waitcnt lgkmcnt(0)" ::: "memory");                                  \
  __builtin_amdgcn_sched_barrier(0)
#define PRIO(x) __builtin_amdgcn_s_setprio(x)

  STG_A(0, 0, 0, 0); STG_A(0, 0, 0, 1); STG_A(0, 0, 1, 0); STG_A(0, 0, 1, 1);
  STG_B(0, 0, 0, 0); STG_B(0, 0, 0, 1); STG_B(0, 0, 1, 0); STG_B(0, 0, 1, 1);
  STG_B(1, 64, 0, 0); STG_B(1, 64, 0, 1); STG_B(1, 64, 1, 0); STG_B(1, 64, 1, 1);
  asm volatile("s_waitcnt vmcnt(4)" ::: "memory");
  BAR();
  __builtin_amdgcn_sched_barrier(0);

  for (int it = 0; it < NIT; ++it) {
    const int T = 2 * it;
    const int pf = (it + 1 < NIT);
    const int kA1 = (T + 1) << 6;
    const int k2 = (T + 2) << 6, k3 = (T + 3) << 6;
    short8 aF[4][2], b0[2][2], b1[2][2];

    // p0
    STG_A(1, kA1, 0, 0); STG_A(1, kA1, 0, 1);
    RDA(0, 0, 0); RDA(1, 0, 0); RDA(2, 0, 0); RDA(3, 0, 0);
    RDB(b0, 0, 0, 0); RDB(b0, 1, 1, 0);
    BAR(); LGK0();
    PRIO(1); MQUAD(b0, 0, 0); PRIO(0);
    BAR();

    // p1
    STG_A(1, kA1, 1, 0); STG_A(1, kA1, 1, 1);
    RDB(b1, 0, 2, 0); RDB(b1, 1, 3, 0);
    BAR(); LGK0();
    PRIO(1); MQUAD(b1, 0, 1); PRIO(0);
    BAR();

    // p2
    if (pf) { STG_B(0, k2, 0, 0); STG_B(0, k2, 0, 1); }
    RDA(0, 1, 0); RDA(1, 1, 0); RDA(2, 1, 0); RDA(3, 1, 0);
    BAR(); LGK0();
    PRIO(1); MQUAD(b0, 1, 0); PRIO(0);
    BAR();

    // p3 ; GATE 1
    if (pf) { STG_B(0, k2, 1, 0); STG_B(0, k2, 1, 1); }
    BAR();
    PRIO(1); MQUAD(b1, 1, 1); PRIO(0);
    if (pf) asm volatile("s_waitcnt vmcnt(4)" ::: "memory");
    else    asm volatile("s_waitcnt vmcnt(0)" ::: "memory");
    BAR();
    __builtin_amdgcn_sched_barrier(0);

    // p4
    if (pf) { STG_A(0, k2, 0, 0); STG_A(0, k2, 0, 1); }
    RDA(0, 0, 1); RDA(1, 0, 1); RDA(2, 0, 1); RDA(3, 0, 1);
    RDB(b0, 0, 0, 1); RDB(b0, 1, 1, 1);
    BAR(); LGK0();
    PRIO(1); MQUAD(b0, 0, 0); PRIO(0);
    BAR();

    // p5
    if (pf) { STG_A(0, k2, 1, 0); STG_A(0, k2, 1, 1); }
    RDB(b1, 0, 2, 1); RDB(b1, 1, 3, 1);
    BAR(); LGK0();
    PRIO(1); MQUAD(b1, 0, 1); PRIO(0);
    BAR();

    // p6
    if (pf) { STG_B(1, k3, 0, 0); STG_B(1, k3, 0, 1); }
    RDA(0, 1, 1); RDA(1, 1, 1); RDA(2, 1, 1); RDA(3, 1, 1);
    BAR(); LGK0();
    PRIO(1); MQUAD(b0, 1, 0); PRIO(0);
    BAR();

    // p7 ; GATE 2 (skipped on final iter)
    if (pf) { STG_B(1, k3, 1, 0); STG_B(1, k3, 1, 1); }
    BAR();
    PRIO(1); MQUAD(b1, 1, 1); PRIO(0);
    if (pf) {
      asm volatile("s_waitcnt vmcnt(4)" ::: "memory");
      BAR();
      __builtin_amdgcn_sched_barrier(0);
    }
  }
#undef STG_A
#undef STG_B
#undef RDA
#undef RDB
#undef MM2
#undef MQUAD

  // acc[i][j][0..3] = C[row = bm+wm*128+i*16+r][col = bn+wn*64+j*16+quad*4 +0..3]
#pragma unroll
  for (int i = 0; i < 8; i++) {
    int rowg = bm + wm * 128 + i * 16 + r;
#pragma unroll
    for (int j = 0; j < 4; j++) {
      int colg = bn + wn * 64 + j * 16 + quad * 4;
      size_t idx = (size_t)rowg * N + colg;
      float v0 = acc[i][j][0], v1 = acc[i][j][1], v2 = acc[i][j][2], v3 = acc[i][j][3];
      if (MODE & 1) {
        float4 bv = *(const float4*)(bias + colg);
        v0 += bv.x; v1 += bv.y; v2 += bv.z; v3 += bv.w;
      }
      if (MODE & 2) {
        v0 = fgelu(v0); v1 = fgelu(v1); v2 = fgelu(v2); v3 = fgelu(v3);
      }
      if (MODE & 4) {
        float4 ev = *(const float4*)(extra + idx);
        v0 += ev.x; v1 += ev.y; v2 += ev.z; v3 += ev.w;
      }
      if (MODE & 16) {
        float4 lb = *(const float4*)(log_beta + colg);
        float4 vi = *(const float4*)(vel_in + idx);
        float4 xi = *(const float4*)(x_in + idx);
        float4 vn;
        vn.x = fmaf(fsig(lb.x), vi.x, v0);
        vn.y = fmaf(fsig(lb.y), vi.y, v1);
        vn.z = fmaf(fsig(lb.z), vi.z, v2);
        vn.w = fmaf(fsig(lb.w), vi.w, v3);
        *(float4*)(vel_out + idx) = vn;
        v0 = xi.x + vn.x; v1 = xi.y + vn.y; v2 = xi.z + vn.z; v3 = xi.w + vn.w;
      }
      if (MODE & 8) {
        uint2 pk;
        pk.x = f2bf(v0) | (f2bf(v1) << 16);
        pk.y = f2bf(v2) | (f2bf(v3) << 16);
        *(uint2*)((unsigned short*)Cout + idx) = pk;
      } else {
        float4 o; o.x = v0; o.y = v1; o.z = v2; o.w = v3;
        *(float4*)((float*)Cout + idx) = o;
      }
    }
  }
}

// ---------------- bf16 MFMA GEMM v6: BN=128, 4-phase, triple-A ---------------
// BM=256, BN=128, BK=64, 512 thr = 8 waves 4M x 2N (wave tile 64x64).
// v5 (8-phase, 8 MFMA/phase) measured MfmaUtil 25% -- half the MFMA:barrier
// ratio of the 16-MFMA/phase bgemm3. v6 merges quadrant pairs: 4 phases per
// 2-K-tile iteration, 16 MFMA/phase, 8 barriers/iter (was 16). Double-buffer
// can't cover the shorter pipeline (gate would hit vmcnt(0)), so A is
// TRIPLE-buffered (3x32K) + B double (2x16K) = 128 KiB. A-buf of tile X =
// X%3; B-buf = X%2 (static: even->b0, odd->b1).
// Stage schedule (race-checked; every region staged >=1 barrier-pair after
// its last reader): ph0: A(T+2)h0 | ph1: A(T+2)h1 + B(T+2)s0, GATE1 |
// ph2: B(T+2)s1 + A(T+3)h0 | ph3: A(T+3)h1 + B(T+3)s0s1, GATE2.
// FIFO invariant entering each iter: 6 loads in flight (A(T+1)x4, B(T+1)x2).
// GATE1 = vmcnt(5) completes exactly A(T+1)+B(T+1); GATE2 = vmcnt(6)
// completes exactly A(T+2)+B(T+2). vmcnt(0) only on the final iteration.
template <int MODE>
__global__ __launch_bounds__(512, 2) void bgemm4_k(const unsigned short* __restrict__ A,
                                                   const unsigned short* __restrict__ BT,
                                                   void* __restrict__ Cout,
                                                   int M, int N, int K,
                                                   const float* __restrict__ bias,
                                                   const float* __restrict__ extra,
                                                   const float* __restrict__ vel_in,
                                                   const float* __restrict__ x_in,
                                                   const float* __restrict__ log_beta,
                                                   float* __restrict__ vel_out) {
  __shared__ unsigned short LA[3][256 * 64];   // 96 KiB (triple A)
  __shared__ unsigned short LB[2][128 * 64];   // 32 KiB
  const int tid = threadIdx.x;
  const int wid = tid >> 6, lane = tid & 63;
  const int wm = wid >> 1, wn = wid & 1;       // 4M x 2N wave grid
  const int r = lane & 15, quad = lane >> 4, r7 = lane & 7;

  const int gx = gridDim.x;
  int id = blockIdx.y * gx + blockIdx.x;
  const int nwg = gx * gridDim.y;
  id = (id & 7) * (nwg >> 3) + (id >> 3);
  const int bm = (id / gx) * 256, bn = (id % gx) * 128;
  const int NIT = K >> 7;

  const int lrow = lane >> 3;
  const int sblk = (lane & 7) ^ lrow;
  const unsigned short* AsrcB = A  + (size_t)(bm + lrow) * K + sblk * 8;
  const unsigned short* BsrcB = BT + (size_t)(bn + lrow) * K + sblk * 8;

  unsigned short* ALDS = &LA[0][0];
  unsigned short* B0 = &LB[0][0];
  unsigned short* B1 = &LB[1][0];

  const int aB = wm * 4096 + r * 64;           // wm*64 rows
  const int bB = wn * 4096 + r * 64;           // wn*64 rows
  const int kq0 = (quad ^ r7) * 8;
  const int kq1 = ((4 + quad) ^ r7) * 8;

  floatx4 acc[4][4];
#pragma unroll
  for (int i = 0; i < 4; i++)
#pragma unroll
    for (int j = 0; j < 4; j++) acc[i][j] = (floatx4){0.f, 0.f, 0.f, 0.f};

#define STG_A6(dst, k0, h, s)                                                         \
  gload_lds16(AsrcB + (size_t)((h) * 128 + (s) * 64 + wid * 8) * K + (k0),            \
              (void*)((dst) + ((h) * 128 + (s) * 64 + wid * 8) * 64))
#define STG_B6(dst, k0, s)                                                            \
  gload_lds16(BsrcB + (size_t)((s) * 64 + wid * 8) * K + (k0),                        \
              (void*)((dst) + ((s) * 64 + wid * 8) * 64))
#define RDA6(src, IH)                                                                 \
  aF[0][0] = *(const short8*)((src) + aB + (IH) * 2048 + kq0);                        \
  aF[0][1] = *(const short8*)((src) + aB + (IH) * 2048 + kq1);                        \
  aF[1][0] = *(const short8*)((src) + aB + (IH) * 2048 + 1024 + kq0);                 \
  aF[1][1] = *(const short8*)((src) + aB + (IH) * 2048 + 1024 + kq1)
#define RDB6(BF, src, JH)                                                             \
  BF[0][0] = *(const short8*)((src) + bB + (JH) * 2048 + kq0);                        \
  BF[0][1] = *(const short8*)((src) + bB + (JH) * 2048 + kq1);                        \
  BF[1][0] = *(const short8*)((src) + bB + (JH) * 2048 + 1024 + kq0);                 \
  BF[1][1] = *(const short8*)((src) + bB + (JH) * 2048 + 1024 + kq1)
#define MM26(il, jl, BF, IH, JH)                                                      \
  acc[(IH) * 2 + (il)][(JH) * 2 + (jl)] = __builtin_amdgcn_mfma_f32_16x16x32_bf16(    \
      BF[jl][0], aF[il][0], acc[(IH) * 2 + (il)][(JH) * 2 + (jl)], 0, 0, 0);          \
  acc[(IH) * 2 + (il)][(JH) * 2 + (jl)] = __builtin_amdgcn_mfma_f32_16x16x32_bf16(    \
      BF[jl][1], aF[il][1], acc[(IH) * 2 + (il)][(JH) * 2 + (jl)], 0, 0, 0)
#define MQ6(BF, IH, JH)                                                               \
  MM26(0, 0, BF, IH, JH); MM26(0, 1, BF, IH, JH);                                     \
  MM26(1, 0, BF, IH, JH); MM26(1, 1, BF, IH, JH)

  // ---- prologue: A(0)->la0, B(0)->b0, A(1)->la1, B(1)->b1 (issue order!)
  STG_A6(ALDS, 0, 0, 0); STG_A6(ALDS, 0, 0, 1); STG_A6(ALDS, 0, 1, 0); STG_A6(ALDS, 0, 1, 1);
  STG_B6(B0, 0, 0); STG_B6(B0, 0, 1);
  STG_A6(ALDS + 16384, 64, 0, 0); STG_A6(ALDS + 16384, 64, 0, 1);
  STG_A6(ALDS + 16384, 64, 1, 0); STG_A6(ALDS + 16384, 64, 1, 1);
  STG_B6(B1, 64, 0); STG_B6(B1, 64, 1);
  asm volatile("s_waitcnt vmcnt(6)" ::: "memory");
  BAR();
  __builtin_amdgcn_sched_barrier(0);

  int p = 0;                                    // A-buf of tile T (=T%3)
  for (int it = 0; it < NIT; ++it) {
    const int T = 2 * it;
    const int pf = (it + 1 < NIT);
    const int k2 = (T + 2) << 6, k3 = (T + 3) << 6;
    const int pn = (p == 2) ? 0 : p + 1;        // (T+1)%3
    const int p2 = (pn == 2) ? 0 : pn + 1;      // (T+2)%3 ; (T+3)%3 == p
    unsigned short* Acur = ALDS + p * 16384;
    unsigned short* Anxt = ALDS + pn * 16384;
    unsigned short* Asg2 = ALDS + p2 * 16384;
    short8 aF[2][2], bR0[2][2], bR1[2][2];

    // ph0: compute T (IH0 x JH0+JH1); stage A(T+2)h0 -> Asg2
    if (pf) { STG_A6(Asg2, k2, 0, 0); STG_A6(Asg2, k2, 0, 1); }
    RDA6(Acur, 0); RDB6(bR0, B0, 0); RDB6(bR1, B0, 1);
    BAR(); LGK0();
    PRIO(1); MQ6(bR0, 0, 0); MQ6(bR1, 0, 1); PRIO(0);
    BAR();

    // ph1: compute T (IH1); stage A(T+2)h1 + B(T+2)s0 ; GATE1
    if (pf) { STG_A6(Asg2, k2, 1, 0); STG_A6(Asg2, k2, 1, 1); STG_B6(B0, k2, 0); }
    RDA6(Acur, 1);
    BAR(); LGK0();
    PRIO(1); MQ6(bR0, 1, 0); MQ6(bR1, 1, 1); PRIO(0);
    if (pf) asm volatile("s_waitcnt vmcnt(5)" ::: "memory");
    else    asm volatile("s_waitcnt vmcnt(0)" ::: "memory");
    BAR();
    __builtin_amdgcn_sched_barrier(0);

    // ph2: compute T+1 (IH0); stage B(T+2)s1 + A(T+3)h0 -> Acur
    if (pf) { STG_B6(B0, k2, 1); STG_A6(Acur, k3, 0, 0); STG_A6(Acur, k3, 0, 1); }
    RDA6(Anxt, 0); RDB6(bR0, B1, 0); RDB6(bR1, B1, 1);
    BAR(); LGK0();
    PRIO(1); MQ6(bR0, 0, 0); MQ6(bR1, 0, 1); PRIO(0);
    BAR();

    // ph3: compute T+1 (IH1); stage A(T+3)h1 + B(T+3)s0s1 ; GATE2 (skip last)
    if (pf) { STG_A6(Acur, k3, 1, 0); STG_A6(Acur, k3, 1, 1);
              STG_B6(B1, k3, 0); STG_B6(B1, k3, 1); }
    RDA6(Anxt, 1);
    BAR(); LGK0();
    PRIO(1); MQ6(bR0, 1, 0); MQ6(bR1, 1, 1); PRIO(0);
    if (pf) {
      asm volatile("s_waitcnt vmcnt(6)" ::: "memory");
      BAR();
      __builtin_amdgcn_sched_barrier(0);
    }
    p = p2;
  }
#undef STG_A6
#undef STG_B6
#undef RDA6
#undef RDB6
#undef MM26
#undef MQ6
#undef BAR
#undef LGK0
#undef PRIO

  // acc[i][j][0..3] = C[row = bm+wm*64+i*16+r][col = bn+wn*64+j*16+quad*4 +0..3]
#pragma unroll
  for (int i = 0; i < 4; i++) {
    int rowg = bm + wm * 64 + i * 16 + r;
#pragma unroll
    for (int j = 0; j < 4; j++) {
      int colg = bn + wn * 64 + j * 16 + quad * 4;
      size_t idx = (size_t)rowg * N + colg;
      float v0 = acc[i][j][0], v1 = acc[i][j][1], v2 = acc[i][j][2], v3 = acc[i][j][3];
      if (MODE & 1) {
        float4 bv = *(const float4*)(bias + colg);
        v0 += bv.x; v1 += bv.y; v2 += bv.z; v3 += bv.w;
      }
      if (MODE & 2) {
        v0 = fgelu(v0); v1 = fgelu(v1); v2 = fgelu(v2); v3 = fgelu(v3);
      }
      if (MODE & 4) {
        float4 ev = *(const float4*)(extra + idx);
        v0 += ev.x; v1 += ev.y; v2 += ev.z; v3 += ev.w;
      }
      if (MODE & 16) {
        float4 lb = *(const float4*)(log_beta + colg);
        float4 vi = *(const float4*)(vel_in + idx);
        float4 xi = *(const float4*)(x_in + idx);
        float4 vn;
        vn.x = fmaf(fsig(lb.x), vi.x, v0);
        vn.y = fmaf(fsig(lb.y), vi.y, v1);
        vn.z = fmaf(fsig(lb.z), vi.z, v2);
        vn.w = fmaf(fsig(lb.w), vi.w, v3);
        *(float4*)(vel_out + idx) = vn;
        v0 = xi.x + vn.x; v1 = xi.y + vn.y; v2 = xi.z + vn.z; v3 = xi.w + vn.w;
      }
      if (MODE & 8) {
        uint2 pk;
        pk.x = f2bf(v0) | (f2bf(v1) << 16);
        pk.y = f2bf(v2) | (f2bf(v3) << 16);
        *(uint2*)((unsigned short*)Cout + idx) = pk;
      } else {
        float4 o; o.x = v0; o.y = v1; o.z = v2; o.w = v3;
        *(float4*)((float*)Cout + idx) = o;
      }
    }
  }
}

// ---------------- scan phase 1: gating + per-chunk (A, h_local) -------------
__global__ __launch_bounds__(256) void scan_p1(const unsigned short* __restrict__ gapre,
                                               const unsigned short* __restrict__ xn,
                                               const float* __restrict__ lam,
                                               unsigned short* __restrict__ ub,
                                               float* __restrict__ carryA,
                                               float* __restrict__ carryH) {
  int g = blockIdx.x * 256 + threadIdx.x;    // 0..131071
  int e = g & (Dd - 1);
  int bc = g >> 10;
  int b = bc & 3;
  int c = bc >> 2;
  float l = lam[e];
  float sp = fmaxf(l, 0.0f) + log1pf(__expf(-fabsf(l)));
  float m8sp = -8.0f * sp;
  size_t m0 = (size_t)b * Ss + (size_t)c * CL;
  float A = 1.0f, h = 0.0f;
#pragma unroll 4
  for (int t = 0; t < CL; t++) {
    size_t m = m0 + t;
    float gp = bf2f(gapre[m * 2048 + e]);
    float ap = bf2f(gapre[m * 2048 + 1024 + e]);
    float xv = bf2f(xn[m * Dd + e]);
    float a = __expf(m8sp * fsig(ap));
    float u = sqrtf(fmaxf(1.0f - a * a, 0.0f)) * fsig(gp) * xv;
    ub[m * Dd + e] = (unsigned short)f2bf(u);
    A *= a;
    h = fmaf(a, h, u);
  }
  carryA[c * 4096 + b * 1024 + e] = A;
  carryH[c * 4096 + b * 1024 + e] = h;
}

// ---------------- scan phase 2: scan carries -> per-chunk init state --------
__global__ __launch_bounds__(256) void scan_p2(const float* __restrict__ carryA,
                                               const float* __restrict__ carryH,
                                               float* __restrict__ init) {
  int ch = blockIdx.x * 256 + threadIdx.x;   // 0..4095
  float H = 0.0f;
#pragma unroll
  for (int c = 0; c < CH; c++) {
    init[c * 4096 + ch] = H;
    H = fmaf(carryA[c * 4096 + ch], H, carryH[c * 4096 + ch]);
  }
}

// ---------------- scan phase 3: rescan chunk with init -> concat[:,D:2D] ----
__global__ __launch_bounds__(256) void scan_p3(const unsigned short* __restrict__ gapre,
                                               const unsigned short* __restrict__ ub,
                                               const float* __restrict__ lam,
                                               const float* __restrict__ init,
                                               unsigned short* __restrict__ outC) {
  int g = blockIdx.x * 256 + threadIdx.x;
  int e = g & (Dd - 1);
  int bc = g >> 10;
  int b = bc & 3;
  int c = bc >> 2;
  float l = lam[e];
  float sp = fmaxf(l, 0.0f) + log1pf(__expf(-fabsf(l)));
  float m8sp = -8.0f * sp;
  size_t m0 = (size_t)b * Ss + (size_t)c * CL;
  float h = init[c * 4096 + b * 1024 + e];
#pragma unroll 4
  for (int t = 0; t < CL; t++) {
    size_t m = m0 + t;
    float ap = bf2f(gapre[m * 2048 + 1024 + e]);
    float a = __expf(m8sp * fsig(ap));
    float u = bf2f(ub[m * Dd + e]);
    h = fmaf(a, h, u);
    outC[m * (2 * Dd) + Dd + e] = (unsigned short)f2bf(h);
  }
}

extern "C" void kernel_launch(void* const* d_in, const int* in_sizes, int n_in,
                              void* d_out, int out_size, void* d_ws, size_t ws_size,
                              hipStream_t stream) {
  const float* x        = (const float*)d_in[0];
  const float* velocity = (const float*)d_in[1];
  const float* pre_w    = (const float*)d_in[2];
  const float* conv_w   = (const float*)d_in[3];
  const float* conv_b   = (const float*)d_in[4];
  const float* W_gate   = (const float*)d_in[5];
  const float* W_a      = (const float*)d_in[6];
  const float* lam      = (const float*)d_in[7];
  const float* W_out    = (const float*)d_in[8];
  const float* b_out    = (const float*)d_in[9];
  const float* log_beta = (const float*)d_in[10];
  const float* ffn_w    = (const float*)d_in[11];
  const float* W_ff1    = (const float*)d_in[12];
  const float* b_ff1    = (const float*)d_in[13];
  const float* W_ff2    = (const float*)d_in[14];
  const float* b_ff2    = (const float*)d_in[15];

  float* out0 = (float*)d_out;
  float* out1 = out0 + ND;

  // ---- workspace (byte offsets), lifetime-aliased; peak 152 MB ----
  const size_t MB = 1024 * 1024;
  char* ws = (char*)d_ws;
  unsigned short* WgaT  = (unsigned short*)ws;               // 2048x1024 [0,4) (gate|a)
  unsigned short* WoT   = WgaT + (size_t)2 * 1024 * 1024;    // [4,8)
  unsigned short* Wf1T  = WoT + (size_t)2 * 1024 * 1024;     // [8,16)
  unsigned short* Wf2T  = Wf1T + (size_t)4 * 1024 * 1024;    // [16,24)
  float*          mixer = (float*)(ws + 24 * MB);            // 32 MB [24,56) — x_new
  float*          carA  = (float*)(ws + 24 * MB);            // overlay (pre-step-6)
  float*          carH  = (float*)(ws + 24 * MB + 512 * 1024);
  float*          initb = (float*)(ws + 25 * MB);
  unsigned short* conc  = (unsigned short*)(ws + 56 * MB);   // 32 MB [56,88)
  unsigned short* gapre = (unsigned short*)(ws + 88 * MB);   // 32 MB [88,120)
  unsigned short* xnbf  = (unsigned short*)(ws + 120 * MB);  // 16 MB [120,136)
  unsigned short* ubf   = (unsigned short*)(ws + 136 * MB);  // 16 MB [136,152)
  unsigned short* midbf = (unsigned short*)(ws + 88 * MB);   // 64 MB overlay [88,152)
  unsigned short* nrmbf = (unsigned short*)(ws + 56 * MB);   // overlay conc

  const int EB = 256;
  const int egrid4 = (int)(ND / 4 / EB);

  // 0. weight transpose + bf16 convert (gate|a combined, contiguous)
  wconv_k<<<dim3(32, 32),  256, 0, stream>>>(W_gate, WgaT, 1024, 1024);
  wconv_k<<<dim3(32, 32),  256, 0, stream>>>(W_a,    WgaT + (size_t)1024 * 1024, 1024, 1024);
  wconv_k<<<dim3(32, 64),  256, 0, stream>>>(W_out,  WoT, 2048, 1024);
  wconv_k<<<dim3(128, 32), 256, 0, stream>>>(W_ff1,  Wf1T, 1024, 4096);
  wconv_k<<<dim3(32, 128), 256, 0, stream>>>(W_ff2,  Wf2T, 4096, 1024);
  // 1. x_norm (bf16)
  rmsnorm_bf_k<<<Mm, 256, 0, stream>>>(x, pre_w, xnbf);
  // 2. conv -> concat[:, 0:D]
  conv_k<<<egrid4, EB, 0, stream>>>(xnbf, conv_w, conv_b, conc);
  // 3. fused gate_pre|a_pre GEMM (N=2048, bf16 out) — 256 blocks, full chip
  bgemm3_k<8><<<dim3(8, 32), 512, 0, stream>>>(xnbf, WgaT, gapre, Mm, 2048, 1024,
      nullptr, nullptr, nullptr, nullptr, nullptr, nullptr);
  // 4-5. chunked scan (gating fused into P1) -> concat[:, D:2D]
  scan_p1<<<512, 256, 0, stream>>>(gapre, xnbf, lam, ubf, carA, carH);
  scan_p2<<<16, 256, 0, stream>>>(carA, carH, initb);
  scan_p3<<<512, 256, 0, stream>>>(gapre, ubf, lam, initb, conc);
  // 6. mixer GEMM (N=1024) -> v6 BN=128, 256 blocks full chip
  bgemm4_k<1 | 16><<<dim3(8, 32), 512, 0, stream>>>(conc, WoT, mixer, Mm, 1024, 2048,
      b_out, nullptr, velocity, x, log_beta, out1);
  // 8. normed = rmsnorm(x_new) (bf16)
  rmsnorm_bf_k<<<Mm, 256, 0, stream>>>(mixer, ffn_w, nrmbf);
  // 9. mid = gelu(normed @ W_ff1 + b_ff1) (bf16) — 512 blocks
  bgemm3_k<1 | 2 | 8><<<dim3(16, 32), 512, 0, stream>>>(nrmbf, Wf1T, midbf, Mm, 4096, 1024,
      b_ff1, nullptr, nullptr, nullptr, nullptr, nullptr);
  // 10. out0 = mid @ W_ff2 + b_ff2 + x_new (fp32, N=1024) -> v6 BN=128
  bgemm4_k<1 | 4><<<dim3(8, 32), 512, 0, stream>>>(midbf, Wf2T, out0, Mm, 1024, 4096,
      b_ff2, mixer, nullptr, nullptr, nullptr, nullptr);
}

// Round 7
// 562.293 us; speedup vs baseline: 1.0969x; 1.0969x over previous
//
#include <hip/hip_runtime.h>

// (B,S,D,K,F) = (4, 2048, 1024, 4, 4096)
static constexpr int Bb = 4;
static constexpr int Ss = 2048;
static constexpr int Dd = 1024;
static constexpr int Ff = 4096;
static constexpr int Mm = Bb * Ss;              // 8192 rows
static constexpr size_t ND = (size_t)Mm * Dd;   // 8388608
static constexpr int CH = 32;                   // scan chunks
static constexpr int CL = Ss / CH;              // chunk length 64

typedef __attribute__((ext_vector_type(8))) short short8;
typedef __attribute__((ext_vector_type(4))) float floatx4;

__device__ __forceinline__ unsigned f2bf(float f) {
  unsigned u = __builtin_bit_cast(unsigned, f);
  return (u + 0x7FFFu + ((u >> 16) & 1u)) >> 16;   // RNE
}
__device__ __forceinline__ float bf2f(unsigned bits) {
  return __builtin_bit_cast(float, bits << 16);
}
__device__ __forceinline__ void gload_lds16(const void* g, void* lds) {
  __builtin_amdgcn_global_load_lds((const __attribute__((address_space(1))) void*)g,
                                   (__attribute__((address_space(3))) void*)lds,
                                   16, 0, 0);
}
// fast sigmoid / tanh-gelu via hw v_exp_f32 + v_rcp_f32 (f32-accurate ~1e-6)
__device__ __forceinline__ float fsig(float x) {
  return __builtin_amdgcn_rcpf(1.0f + __expf(-x));
}
__device__ __forceinline__ float fgelu(float v) {
  float z = 1.5957691216057308f * fmaf(0.044715f * v, v * v, v);
  return v * __builtin_amdgcn_rcpf(1.0f + __expf(-z));
}

// ---------------- weight transpose + fp32->bf16: W[K][N] -> WT[N][K] --------
__global__ __launch_bounds__(256) void wconv_k(const float* __restrict__ W,
                                               unsigned short* __restrict__ WT,
                                               int K, int N) {
  __shared__ float tile[32][33];
  int tx = threadIdx.x & 31, ty = threadIdx.x >> 5;
  int bx = blockIdx.x * 32, by = blockIdx.y * 32;
#pragma unroll
  for (int i = 0; i < 32; i += 8)
    tile[ty + i][tx] = W[(size_t)(by + ty + i) * N + bx + tx];
  __syncthreads();
#pragma unroll
  for (int i = 0; i < 32; i += 8)
    WT[(size_t)(bx + ty + i) * K + by + tx] = (unsigned short)f2bf(tile[tx][ty + i]);
}

// ---------------- RMSNorm: fp32 in, bf16 out --------------------------------
__global__ __launch_bounds__(256) void rmsnorm_bf_k(const float* __restrict__ x,
                                                    const float* __restrict__ w,
                                                    unsigned short* __restrict__ out) {
  int row = blockIdx.x;
  const float4* xr = (const float4*)(x + (size_t)row * Dd);
  int t = threadIdx.x;
  float4 v = xr[t];
  float ss = v.x * v.x + v.y * v.y + v.z * v.z + v.w * v.w;
#pragma unroll
  for (int off = 32; off > 0; off >>= 1) ss += __shfl_down(ss, off, 64);
  __shared__ float sb[4];
  if ((t & 63) == 0) sb[t >> 6] = ss;
  __syncthreads();
  float tot = sb[0] + sb[1] + sb[2] + sb[3];
  float sc = rsqrtf(tot * (1.0f / (float)Dd) + 1e-6f);
  float4 wv = ((const float4*)w)[t];
  unsigned lo = f2bf(v.x * sc * wv.x) | (f2bf(v.y * sc * wv.y) << 16);
  unsigned hi = f2bf(v.z * sc * wv.z) | (f2bf(v.w * sc * wv.w) << 16);
  *(uint2*)(out + (size_t)row * Dd + t * 4) = make_uint2(lo, hi);
}

// ---------------- Causal depthwise conv (bf16 in/out) -> concat[:,0:D] ------
__global__ __launch_bounds__(256) void conv_k(const unsigned short* __restrict__ xn,
                                              const float* __restrict__ kern,
                                              const float* __restrict__ bias,
                                              unsigned short* __restrict__ outC) {
  size_t q = (size_t)blockIdx.x * 256 + threadIdx.x;  // over ND/4
  size_t i = q * 4;
  int d = (int)(i & (Dd - 1));
  int m = (int)(i >> 10);
  int t = m & (Ss - 1);
  float acc[4];
#pragma unroll
  for (int j = 0; j < 4; j++) acc[j] = bias[d + j];
#pragma unroll
  for (int k = 0; k < 4; k++) {
    if (t >= k) {
      uint2 xv = *(const uint2*)(xn + i - (size_t)k * Dd);
      float x0 = bf2f(xv.x & 0xFFFF), x1 = bf2f(xv.x >> 16);
      float x2 = bf2f(xv.y & 0xFFFF), x3 = bf2f(xv.y >> 16);
      acc[0] = fmaf(kern[(d + 0) * 4 + k], x0, acc[0]);
      acc[1] = fmaf(kern[(d + 1) * 4 + k], x1, acc[1]);
      acc[2] = fmaf(kern[(d + 2) * 4 + k], x2, acc[2]);
      acc[3] = fmaf(kern[(d + 3) * 4 + k], x3, acc[3]);
    }
  }
  unsigned lo = f2bf(acc[0]) | (f2bf(acc[1]) << 16);
  unsigned hi = f2bf(acc[2]) | (f2bf(acc[3]) << 16);
  *(uint2*)(outC + (size_t)m * (2 * Dd) + d) = make_uint2(lo, hi);
}

// ---------------- bf16 MFMA GEMM v4: m201-style 8-phase 256x256 template ----
// (unchanged -- measured r4/r5: FETCH collapse, 0 bank conflicts, VGPR=128)
// MODE bits: 1=+bias[col], 2=gelu, 4=+extra (fp32), 8=bf16 out, 16=velocity
template <int MODE>
__global__ __launch_bounds__(512, 2) void bgemm3_k(const unsigned short* __restrict__ A,
                                                   const unsigned short* __restrict__ BT,
                                                   void* __restrict__ Cout,
                                                   int M, int N, int K,
                                                   const float* __restrict__ bias,
                                                   const float* __restrict__ extra,
                                                   const float* __restrict__ vel_in,
                                                   const float* __restrict__ x_in,
                                                   const float* __restrict__ log_beta,
                                                   float* __restrict__ vel_out) {
  __shared__ unsigned short LA[2][256 * 64];   // 64 KiB
  __shared__ unsigned short LB[2][256 * 64];   // 64 KiB
  const int tid = threadIdx.x;
  const int wid = tid >> 6, lane = tid & 63;
  const int wm = wid >> 2, wn = wid & 3;       // 2M x 4N wave grid
  const int r = lane & 15, quad = lane >> 4, r7 = lane & 7;

  const int gx = gridDim.x;
  int id = blockIdx.y * gx + blockIdx.x;
  const int nwg = gx * gridDim.y;
  id = (id & 7) * (nwg >> 3) + (id >> 3);
  const int bm = (id / gx) * 256, bn = (id % gx) * 256;
  const int NIT = K >> 7;                      // iterations of 2 K-tiles

  const int lrow = lane >> 3;
  const int sblk = (lane & 7) ^ lrow;          // pre-swizzled 16B block index
  const unsigned short* AsrcB = A  + (size_t)(bm + lrow) * K + sblk * 8;
  const unsigned short* BsrcB = BT + (size_t)(bn + lrow) * K + sblk * 8;

  const int aB = wm * 8192 + r * 64;
  const int bB = wn * 4096 + r * 64;
  const int kq0 = (quad ^ r7) * 8;
  const int kq1 = ((4 + quad) ^ r7) * 8;

  floatx4 acc[8][4];
#pragma unroll
  for (int i = 0; i < 8; i++)
#pragma unroll
    for (int j = 0; j < 4; j++) acc[i][j] = (floatx4){0.f, 0.f, 0.f, 0.f};

#define STG_A(bq, k0, h, s)                                                           \
  gload_lds16(AsrcB + (size_t)((h) * 128 + (s) * 64 + wid * 8) * K + (k0),            \
              (void*)&LA[bq][((h) * 128 + (s) * 64 + wid * 8) * 64])
#define STG_B(bq, k0, h, s)                                                           \
  gload_lds16(BsrcB + (size_t)((h) * 128 + (s) * 64 + wid * 8) * K + (k0),            \
              (void*)&LB[bq][((h) * 128 + (s) * 64 + wid * 8) * 64])
#define RDA(il, IH, buf)                                                              \
  aF[il][0] = *(const short8*)&LA[buf][aB + (IH) * 4096 + (il) * 1024 + kq0];         \
  aF[il][1] = *(const short8*)&LA[buf][aB + (IH) * 4096 + (il) * 1024 + kq1]
#define RDB(BF, jl, jg, buf)                                                          \
  BF[jl][0] = *(const short8*)&LB[buf][bB + (jg) * 1024 + kq0];                       \
  BF[jl][1] = *(const short8*)&LB[buf][bB + (jg) * 1024 + kq1]
#define MM2(il, jl, BF, IH, JH)                                                       \
  acc[(IH) * 4 + (il)][(JH) * 2 + (jl)] = __builtin_amdgcn_mfma_f32_16x16x32_bf16(    \
      BF[jl][0], aF[il][0], acc[(IH) * 4 + (il)][(JH) * 2 + (jl)], 0, 0, 0);          \
  acc[(IH) * 4 + (il)][(JH) * 2 + (jl)] = __builtin_amdgcn_mfma_f32_16x16x32_bf16(    \
      BF[jl][1], aF[il][1], acc[(IH) * 4 + (il)][(JH) * 2 + (jl)], 0, 0, 0)
#define MQUAD(BF, IH, JH)                                                             \
  MM2(0, 0, BF, IH, JH); MM2(0, 1, BF, IH, JH); MM2(1, 0, BF, IH, JH);                \
  MM2(1, 1, BF, IH, JH); MM2(2, 0, BF, IH, JH); MM2(2, 1, BF, IH, JH);                \
  MM2(3, 0, BF, IH, JH); MM2(3, 1, BF, IH, JH)
#define BAR() __builtin_amdgcn_s_barrier()
#define LGK0()                                                                        \
  asm volatile("s_waitcnt lgkmcnt(0)" ::: "memory");                                  \
  __builtin_amdgcn_sched_barrier(0)
#define PRIO(x) __builtin_amdgcn_s_setprio(x)

  STG_A(0, 0, 0, 0); STG_A(0, 0, 0, 1); STG_A(0, 0, 1, 0); STG_A(0, 0, 1, 1);
  STG_B(0, 0, 0, 0); STG_B(0, 0, 0, 1); STG_B(0, 0, 1, 0); STG_B(0, 0, 1, 1);
  STG_B(1, 64, 0, 0); STG_B(1, 64, 0, 1); STG_B(1, 64, 1, 0); STG_B(1, 64, 1, 1);
  asm volatile("s_waitcnt vmcnt(4)" ::: "memory");
  BAR();
  __builtin_amdgcn_sched_barrier(0);

  for (int it = 0; it < NIT; ++it) {
    const int T = 2 * it;
    const int pf = (it + 1 < NIT);
    const int kA1 = (T + 1) << 6;
    const int k2 = (T + 2) << 6, k3 = (T + 3) << 6;
    short8 aF[4][2], b0[2][2], b1[2][2];

    // p0
    STG_A(1, kA1, 0, 0); STG_A(1, kA1, 0, 1);
    RDA(0, 0, 0); RDA(1, 0, 0); RDA(2, 0, 0); RDA(3, 0, 0);
    RDB(b0, 0, 0, 0); RDB(b0, 1, 1, 0);
    BAR(); LGK0();
    PRIO(1); MQUAD(b0, 0, 0); PRIO(0);
    BAR();

    // p1
    STG_A(1, kA1, 1, 0); STG_A(1, kA1, 1, 1);
    RDB(b1, 0, 2, 0); RDB(b1, 1, 3, 0);
    BAR(); LGK0();
    PRIO(1); MQUAD(b1, 0, 1); PRIO(0);
    BAR();

    // p2
    if (pf) { STG_B(0, k2, 0, 0); STG_B(0, k2, 0, 1); }
    RDA(0, 1, 0); RDA(1, 1, 0); RDA(2, 1, 0); RDA(3, 1, 0);
    BAR(); LGK0();
    PRIO(1); MQUAD(b0, 1, 0); PRIO(0);
    BAR();

    // p3 ; GATE 1
    if (pf) { STG_B(0, k2, 1, 0); STG_B(0, k2, 1, 1); }
    BAR();
    PRIO(1); MQUAD(b1, 1, 1); PRIO(0);
    if (pf) asm volatile("s_waitcnt vmcnt(4)" ::: "memory");
    else    asm volatile("s_waitcnt vmcnt(0)" ::: "memory");
    BAR();
    __builtin_amdgcn_sched_barrier(0);

    // p4
    if (pf) { STG_A(0, k2, 0, 0); STG_A(0, k2, 0, 1); }
    RDA(0, 0, 1); RDA(1, 0, 1); RDA(2, 0, 1); RDA(3, 0, 1);
    RDB(b0, 0, 0, 1); RDB(b0, 1, 1, 1);
    BAR(); LGK0();
    PRIO(1); MQUAD(b0, 0, 0); PRIO(0);
    BAR();

    // p5
    if (pf) { STG_A(0, k2, 1, 0); STG_A(0, k2, 1, 1); }
    RDB(b1, 0, 2, 1); RDB(b1, 1, 3, 1);
    BAR(); LGK0();
    PRIO(1); MQUAD(b1, 0, 1); PRIO(0);
    BAR();

    // p6
    if (pf) { STG_B(1, k3, 0, 0); STG_B(1, k3, 0, 1); }
    RDA(0, 1, 1); RDA(1, 1, 1); RDA(2, 1, 1); RDA(3, 1, 1);
    BAR(); LGK0();
    PRIO(1); MQUAD(b0, 1, 0); PRIO(0);
    BAR();

    // p7 ; GATE 2 (skipped on final iter)
    if (pf) { STG_B(1, k3, 1, 0); STG_B(1, k3, 1, 1); }
    BAR();
    PRIO(1); MQUAD(b1, 1, 1); PRIO(0);
    if (pf) {
      asm volatile("s_waitcnt vmcnt(4)" ::: "memory");
      BAR();
      __builtin_amdgcn_sched_barrier(0);
    }
  }
#undef STG_A
#undef STG_B
#undef RDA
#undef RDB
#undef MM2
#undef MQUAD

  // acc[i][j][0..3] = C[row = bm+wm*128+i*16+r][col = bn+wn*64+j*16+quad*4 +0..3]
#pragma unroll
  for (int i = 0; i < 8; i++) {
    int rowg = bm + wm * 128 + i * 16 + r;
#pragma unroll
    for (int j = 0; j < 4; j++) {
      int colg = bn + wn * 64 + j * 16 + quad * 4;
      size_t idx = (size_t)rowg * N + colg;
      float v0 = acc[i][j][0], v1 = acc[i][j][1], v2 = acc[i][j][2], v3 = acc[i][j][3];
      if (MODE & 1) {
        float4 bv = *(const float4*)(bias + colg);
        v0 += bv.x; v1 += bv.y; v2 += bv.z; v3 += bv.w;
      }
      if (MODE & 2) {
        v0 = fgelu(v0); v1 = fgelu(v1); v2 = fgelu(v2); v3 = fgelu(v3);
      }
      if (MODE & 4) {
        float4 ev = *(const float4*)(extra + idx);
        v0 += ev.x; v1 += ev.y; v2 += ev.z; v3 += ev.w;
      }
      if (MODE & 16) {
        float4 lb = *(const float4*)(log_beta + colg);
        float4 vi = *(const float4*)(vel_in + idx);
        float4 xi = *(const float4*)(x_in + idx);
        float4 vn;
        vn.x = fmaf(fsig(lb.x), vi.x, v0);
        vn.y = fmaf(fsig(lb.y), vi.y, v1);
        vn.z = fmaf(fsig(lb.z), vi.z, v2);
        vn.w = fmaf(fsig(lb.w), vi.w, v3);
        *(float4*)(vel_out + idx) = vn;
        v0 = xi.x + vn.x; v1 = xi.y + vn.y; v2 = xi.z + vn.z; v3 = xi.w + vn.w;
      }
      if (MODE & 8) {
        uint2 pk;
        pk.x = f2bf(v0) | (f2bf(v1) << 16);
        pk.y = f2bf(v2) | (f2bf(v3) << 16);
        *(uint2*)((unsigned short*)Cout + idx) = pk;
      } else {
        float4 o; o.x = v0; o.y = v1; o.z = v2; o.w = v3;
        *(float4*)((float*)Cout + idx) = o;
      }
    }
  }
}

// ---------------- bf16 MFMA GEMM v7: BN=128, v5 8-phase + triple-A ring ------
// BM=256, BN=128, BK=64, 512 thr = 8 waves 4M x 2N (wave tile 64x64).
// v5 measured 106us/25% MfmaUtil, nothing saturated -> latency-bound; its A
// lead time was only 3-4 phases (~1000cy) vs ~900cy HBM latency. v6's coarse
// 4-phase fix REGRESSED (125us: serial LDS bursts per phase). v7 keeps the
// proven v5 8-phase skeleton verbatim and ONLY deepens A to a 3-slot ring:
//   p0/p1: stage A(T+2)->a2 (consumed NEXT iter p4: 12-phase lead)
//   p2/p3: stage B(T+2)->B0 (unchanged v5, 5-6 phase lead)
//   p4/p5: stage A(T+3)->a0 (slot of A(T), dead after p2+p3 barrier)
//   p6/p7: stage B(T+3)->B1 (unchanged v5)
// FIFO invariant entering each iter: 6 in flight (A(T+1)x4 + B(T+1)x2).
// GATE1 (p3) = vmcnt(6): completes exactly A(T+1)+B(T+1) (consumed p4).
// GATE2 (p7) = vmcnt(6): completes exactly A(T+2)+B(T+2) (consumed next p0).
// vmcnt(0) only on the final iteration. Slot rotation (a0,a1,a2)<-(a2,a0,a1).
// LDS = 3x32K (A) + 2x16K (B) = 128 KiB, 1 block/CU.
template <int MODE>
__global__ __launch_bounds__(512, 2) void bgemm4_k(const unsigned short* __restrict__ A,
                                                   const unsigned short* __restrict__ BT,
                                                   void* __restrict__ Cout,
                                                   int M, int N, int K,
                                                   const float* __restrict__ bias,
                                                   const float* __restrict__ extra,
                                                   const float* __restrict__ vel_in,
                                                   const float* __restrict__ x_in,
                                                   const float* __restrict__ log_beta,
                                                   float* __restrict__ vel_out) {
  __shared__ unsigned short LA[3][256 * 64];   // 96 KiB (triple-A ring)
  __shared__ unsigned short LB[2][128 * 64];   // 32 KiB
  const int tid = threadIdx.x;
  const int wid = tid >> 6, lane = tid & 63;
  const int wm = wid >> 1, wn = wid & 1;       // 4M x 2N wave grid
  const int r = lane & 15, quad = lane >> 4, r7 = lane & 7;

  const int gx = gridDim.x;
  int id = blockIdx.y * gx + blockIdx.x;
  const int nwg = gx * gridDim.y;
  id = (id & 7) * (nwg >> 3) + (id >> 3);
  const int bm = (id / gx) * 256, bn = (id % gx) * 128;
  const int NIT = K >> 7;

  const int lrow = lane >> 3;
  const int sblk = (lane & 7) ^ lrow;
  const unsigned short* AsrcB = A  + (size_t)(bm + lrow) * K + sblk * 8;
  const unsigned short* BsrcB = BT + (size_t)(bn + lrow) * K + sblk * 8;

  unsigned short* a0 = &LA[0][0];              // slot of tile T
  unsigned short* a1 = &LA[1][0];              // slot of tile T+1
  unsigned short* a2 = &LA[2][0];              // stage target for T+2
  unsigned short* B0 = &LB[0][0];
  unsigned short* B1 = &LB[1][0];

  const int aB = wm * 4096 + r * 64;           // wm*64 rows
  const int bB = wn * 4096 + r * 64;           // wn*64 rows
  const int kq0 = (quad ^ r7) * 8;
  const int kq1 = ((4 + quad) ^ r7) * 8;

  floatx4 acc[4][4];
#pragma unroll
  for (int i = 0; i < 4; i++)
#pragma unroll
    for (int j = 0; j < 4; j++) acc[i][j] = (floatx4){0.f, 0.f, 0.f, 0.f};

#define STG_A7(dst, k0, h, s)                                                         \
  gload_lds16(AsrcB + (size_t)((h) * 128 + (s) * 64 + wid * 8) * K + (k0),            \
              (void*)((dst) + ((h) * 128 + (s) * 64 + wid * 8) * 64))
#define STG_B7(dst, k0, s)                                                            \
  gload_lds16(BsrcB + (size_t)((s) * 64 + wid * 8) * K + (k0),                        \
              (void*)((dst) + ((s) * 64 + wid * 8) * 64))
#define RDA7(src, IH)                                                                 \
  aF[0][0] = *(const short8*)((src) + aB + (IH) * 2048 + kq0);                        \
  aF[0][1] = *(const short8*)((src) + aB + (IH) * 2048 + kq1);                        \
  aF[1][0] = *(const short8*)((src) + aB + (IH) * 2048 + 1024 + kq0);                 \
  aF[1][1] = *(const short8*)((src) + aB + (IH) * 2048 + 1024 + kq1)
#define RDB7(BF, src, JH)                                                             \
  BF[0][0] = *(const short8*)((src) + bB + (JH) * 2048 + kq0);                        \
  BF[0][1] = *(const short8*)((src) + bB + (JH) * 2048 + kq1);                        \
  BF[1][0] = *(const short8*)((src) + bB + (JH) * 2048 + 1024 + kq0);                 \
  BF[1][1] = *(const short8*)((src) + bB + (JH) * 2048 + 1024 + kq1)
#define MM27(il, jl, BF, IH, JH)                                                      \
  acc[(IH) * 2 + (il)][(JH) * 2 + (jl)] = __builtin_amdgcn_mfma_f32_16x16x32_bf16(    \
      BF[jl][0], aF[il][0], acc[(IH) * 2 + (il)][(JH) * 2 + (jl)], 0, 0, 0);          \
  acc[(IH) * 2 + (il)][(JH) * 2 + (jl)] = __builtin_amdgcn_mfma_f32_16x16x32_bf16(    \
      BF[jl][1], aF[il][1], acc[(IH) * 2 + (il)][(JH) * 2 + (jl)], 0, 0, 0)
#define MQ7(BF, IH, JH)                                                               \
  MM27(0, 0, BF, IH, JH); MM27(0, 1, BF, IH, JH);                                     \
  MM27(1, 0, BF, IH, JH); MM27(1, 1, BF, IH, JH)

  // ---- prologue: A(0)->a0, B(0)->B0, A(1)->a1, B(1)->B1 (issue order!)
  STG_A7(a0, 0, 0, 0); STG_A7(a0, 0, 0, 1); STG_A7(a0, 0, 1, 0); STG_A7(a0, 0, 1, 1);
  STG_B7(B0, 0, 0); STG_B7(B0, 0, 1);
  STG_A7(a1, 64, 0, 0); STG_A7(a1, 64, 0, 1); STG_A7(a1, 64, 1, 0); STG_A7(a1, 64, 1, 1);
  STG_B7(B1, 64, 0); STG_B7(B1, 64, 1);
  asm volatile("s_waitcnt vmcnt(6)" ::: "memory");
  BAR();
  __builtin_amdgcn_sched_barrier(0);

  for (int it = 0; it < NIT; ++it) {
    const int T = 2 * it;
    const int pf = (it + 1 < NIT);
    const int k2 = (T + 2) << 6, k3 = (T + 3) << 6;
    short8 aF[2][2], b0f[2][2], b1f[2][2];

    // p0: stage A(T+2)h0 -> a2 ; read A(T)q0 (a0) + B(T)j01 (B0); MFMA (0,0)
    if (pf) { STG_A7(a2, k2, 0, 0); STG_A7(a2, k2, 0, 1); }
    RDA7(a0, 0); RDB7(b0f, B0, 0);
    BAR(); LGK0();
    PRIO(1); MQ7(b0f, 0, 0); PRIO(0);
    BAR();

    // p1: stage A(T+2)h1 -> a2 ; read B(T)j23; MFMA (0,1)
    if (pf) { STG_A7(a2, k2, 1, 0); STG_A7(a2, k2, 1, 1); }
    RDB7(b1f, B0, 1);
    BAR(); LGK0();
    PRIO(1); MQ7(b1f, 0, 1); PRIO(0);
    BAR();

    // p2: stage B(T+2)s0 -> B0 (B(T) reads done at p1) ; read A(T)q1; MFMA (1,0)
    if (pf) STG_B7(B0, k2, 0);
    RDA7(a0, 1);
    BAR(); LGK0();
    PRIO(1); MQ7(b0f, 1, 0); PRIO(0);
    BAR();

    // p3: stage B(T+2)s1 -> B0 ; MFMA (1,1) ; GATE1: complete A(T+1)+B(T+1)
    if (pf) STG_B7(B0, k2, 1);
    BAR();
    PRIO(1); MQ7(b1f, 1, 1); PRIO(0);
    if (pf) asm volatile("s_waitcnt vmcnt(6)" ::: "memory");
    else    asm volatile("s_waitcnt vmcnt(0)" ::: "memory");
    BAR();
    __builtin_amdgcn_sched_barrier(0);

    // p4: stage A(T+3)h0 -> a0 (A(T) dead after p2+p3 barrier) ;
    //     read A(T+1)q0 (a1) + B(T+1)j01 (B1); MFMA (0,0)
    if (pf) { STG_A7(a0, k3, 0, 0); STG_A7(a0, k3, 0, 1); }
    RDA7(a1, 0); RDB7(b0f, B1, 0);
    BAR(); LGK0();
    PRIO(1); MQ7(b0f, 0, 0); PRIO(0);
    BAR();

    // p5: stage A(T+3)h1 -> a0 ; read B(T+1)j23; MFMA (0,1)
    if (pf) { STG_A7(a0, k3, 1, 0); STG_A7(a0, k3, 1, 1); }
    RDB7(b1f, B1, 1);
    BAR(); LGK0();
    PRIO(1); MQ7(b1f, 0, 1); PRIO(0);
    BAR();

    // p6: stage B(T+3)s0 -> B1 (B(T+1) reads done at p5) ; read A(T+1)q1; MFMA (1,0)
    if (pf) STG_B7(B1, k3, 0);
    RDA7(a1, 1);
    BAR(); LGK0();
    PRIO(1); MQ7(b0f, 1, 0); PRIO(0);
    BAR();

    // p7: stage B(T+3)s1 -> B1 ; MFMA (1,1) ; GATE2: complete A(T+2)+B(T+2)
    if (pf) STG_B7(B1, k3, 1);
    BAR();
    PRIO(1); MQ7(b1f, 1, 1); PRIO(0);
    if (pf) {
      asm volatile("s_waitcnt vmcnt(6)" ::: "memory");
      BAR();
      __builtin_amdgcn_sched_barrier(0);
    }

    // rotate A ring: new T -> old a2 (holds T+2); new T+1 -> old a0 (T+3)
    unsigned short* tmp = a2; a2 = a1; a1 = a0; a0 = tmp;
  }
#undef STG_A7
#undef STG_B7
#undef RDA7
#undef RDB7
#undef MM27
#undef MQ7
#undef BAR
#undef LGK0
#undef PRIO

  // acc[i][j][0..3] = C[row = bm+wm*64+i*16+r][col = bn+wn*64+j*16+quad*4 +0..3]
#pragma unroll
  for (int i = 0; i < 4; i++) {
    int rowg = bm + wm * 64 + i * 16 + r;
#pragma unroll
    for (int j = 0; j < 4; j++) {
      int colg = bn + wn * 64 + j * 16 + quad * 4;
      size_t idx = (size_t)rowg * N + colg;
      float v0 = acc[i][j][0], v1 = acc[i][j][1], v2 = acc[i][j][2], v3 = acc[i][j][3];
      if (MODE & 1) {
        float4 bv = *(const float4*)(bias + colg);
        v0 += bv.x; v1 += bv.y; v2 += bv.z; v3 += bv.w;
      }
      if (MODE & 2) {
        v0 = fgelu(v0); v1 = fgelu(v1); v2 = fgelu(v2); v3 = fgelu(v3);
      }
      if (MODE & 4) {
        float4 ev = *(const float4*)(extra + idx);
        v0 += ev.x; v1 += ev.y; v2 += ev.z; v3 += ev.w;
      }
      if (MODE & 16) {
        float4 lb = *(const float4*)(log_beta + colg);
        float4 vi = *(const float4*)(vel_in + idx);
        float4 xi = *(const float4*)(x_in + idx);
        float4 vn;
        vn.x = fmaf(fsig(lb.x), vi.x, v0);
        vn.y = fmaf(fsig(lb.y), vi.y, v1);
        vn.z = fmaf(fsig(lb.z), vi.z, v2);
        vn.w = fmaf(fsig(lb.w), vi.w, v3);
        *(float4*)(vel_out + idx) = vn;
        v0 = xi.x + vn.x; v1 = xi.y + vn.y; v2 = xi.z + vn.z; v3 = xi.w + vn.w;
      }
      if (MODE & 8) {
        uint2 pk;
        pk.x = f2bf(v0) | (f2bf(v1) << 16);
        pk.y = f2bf(v2) | (f2bf(v3) << 16);
        *(uint2*)((unsigned short*)Cout + idx) = pk;
      } else {
        float4 o; o.x = v0; o.y = v1; o.z = v2; o.w = v3;
        *(float4*)((float*)Cout + idx) = o;
      }
    }
  }
}

// ---------------- scan phase 1: gating + per-chunk (A, h_local) -------------
__global__ __launch_bounds__(256) void scan_p1(const unsigned short* __restrict__ gapre,
                                               const unsigned short* __restrict__ xn,
                                               const float* __restrict__ lam,
                                               unsigned short* __restrict__ ub,
                                               float* __restrict__ carryA,
                                               float* __restrict__ carryH) {
  int g = blockIdx.x * 256 + threadIdx.x;    // 0..131071
  int e = g & (Dd - 1);
  int bc = g >> 10;
  int b = bc & 3;
  int c = bc >> 2;
  float l = lam[e];
  float sp = fmaxf(l, 0.0f) + log1pf(__expf(-fabsf(l)));
  float m8sp = -8.0f * sp;
  size_t m0 = (size_t)b * Ss + (size_t)c * CL;
  float A = 1.0f, h = 0.0f;
#pragma unroll 4
  for (int t = 0; t < CL; t++) {
    size_t m = m0 + t;
    float gp = bf2f(gapre[m * 2048 + e]);
    float ap = bf2f(gapre[m * 2048 + 1024 + e]);
    float xv = bf2f(xn[m * Dd + e]);
    float a = __expf(m8sp * fsig(ap));
    float u = sqrtf(fmaxf(1.0f - a * a, 0.0f)) * fsig(gp) * xv;
    ub[m * Dd + e] = (unsigned short)f2bf(u);
    A *= a;
    h = fmaf(a, h, u);
  }
  carryA[c * 4096 + b * 1024 + e] = A;
  carryH[c * 4096 + b * 1024 + e] = h;
}

// ---------------- scan phase 2: scan carries -> per-chunk init state --------
__global__ __launch_bounds__(256) void scan_p2(const float* __restrict__ carryA,
                                               const float* __restrict__ carryH,
                                               float* __restrict__ init) {
  int ch = blockIdx.x * 256 + threadIdx.x;   // 0..4095
  float H = 0.0f;
#pragma unroll
  for (int c = 0; c < CH; c++) {
    init[c * 4096 + ch] = H;
    H = fmaf(carryA[c * 4096 + ch], H, carryH[c * 4096 + ch]);
  }
}

// ---------------- scan phase 3: rescan chunk with init -> concat[:,D:2D] ----
__global__ __launch_bounds__(256) void scan_p3(const unsigned short* __restrict__ gapre,
                                               const unsigned short* __restrict__ ub,
                                               const float* __restrict__ lam,
                                               const float* __restrict__ init,
                                               unsigned short* __restrict__ outC) {
  int g = blockIdx.x * 256 + threadIdx.x;
  int e = g & (Dd - 1);
  int bc = g >> 10;
  int b = bc & 3;
  int c = bc >> 2;
  float l = lam[e];
  float sp = fmaxf(l, 0.0f) + log1pf(__expf(-fabsf(l)));
  float m8sp = -8.0f * sp;
  size_t m0 = (size_t)b * Ss + (size_t)c * CL;
  float h = init[c * 4096 + b * 1024 + e];
#pragma unroll 4
  for (int t = 0; t < CL; t++) {
    size_t m = m0 + t;
    float ap = bf2f(gapre[m * 2048 + 1024 + e]);
    float a = __expf(m8sp * fsig(ap));
    float u = bf2f(ub[m * Dd + e]);
    h = fmaf(a, h, u);
    outC[m * (2 * Dd) + Dd + e] = (unsigned short)f2bf(h);
  }
}

extern "C" void kernel_launch(void* const* d_in, const int* in_sizes, int n_in,
                              void* d_out, int out_size, void* d_ws, size_t ws_size,
                              hipStream_t stream) {
  const float* x        = (const float*)d_in[0];
  const float* velocity = (const float*)d_in[1];
  const float* pre_w    = (const float*)d_in[2];
  const float* conv_w   = (const float*)d_in[3];
  const float* conv_b   = (const float*)d_in[4];
  const float* W_gate   = (const float*)d_in[5];
  const float* W_a      = (const float*)d_in[6];
  const float* lam      = (const float*)d_in[7];
  const float* W_out    = (const float*)d_in[8];
  const float* b_out    = (const float*)d_in[9];
  const float* log_beta = (const float*)d_in[10];
  const float* ffn_w    = (const float*)d_in[11];
  const float* W_ff1    = (const float*)d_in[12];
  const float* b_ff1    = (const float*)d_in[13];
  const float* W_ff2    = (const float*)d_in[14];
  const float* b_ff2    = (const float*)d_in[15];

  float* out0 = (float*)d_out;
  float* out1 = out0 + ND;

  // ---- workspace (byte offsets), lifetime-aliased; peak 152 MB ----
  const size_t MB = 1024 * 1024;
  char* ws = (char*)d_ws;
  unsigned short* WgaT  = (unsigned short*)ws;               // 2048x1024 [0,4) (gate|a)
  unsigned short* WoT   = WgaT + (size_t)2 * 1024 * 1024;    // [4,8)
  unsigned short* Wf1T  = WoT + (size_t)2 * 1024 * 1024;     // [8,16)
  unsigned short* Wf2T  = Wf1T + (size_t)4 * 1024 * 1024;    // [16,24)
  float*          mixer = (float*)(ws + 24 * MB);            // 32 MB [24,56) — x_new
  float*          carA  = (float*)(ws + 24 * MB);            // overlay (pre-step-6)
  float*          carH  = (float*)(ws + 24 * MB + 512 * 1024);
  float*          initb = (float*)(ws + 25 * MB);
  unsigned short* conc  = (unsigned short*)(ws + 56 * MB);   // 32 MB [56,88)
  unsigned short* gapre = (unsigned short*)(ws + 88 * MB);   // 32 MB [88,120)
  unsigned short* xnbf  = (unsigned short*)(ws + 120 * MB);  // 16 MB [120,136)
  unsigned short* ubf   = (unsigned short*)(ws + 136 * MB);  // 16 MB [136,152)
  unsigned short* midbf = (unsigned short*)(ws + 88 * MB);   // 64 MB overlay [88,152)
  unsigned short* nrmbf = (unsigned short*)(ws + 56 * MB);   // overlay conc

  const int EB = 256;
  const int egrid4 = (int)(ND / 4 / EB);

  // 0. weight transpose + bf16 convert (gate|a combined, contiguous)
  wconv_k<<<dim3(32, 32),  256, 0, stream>>>(W_gate, WgaT, 1024, 1024);
  wconv_k<<<dim3(32, 32),  256, 0, stream>>>(W_a,    WgaT + (size_t)1024 * 1024, 1024, 1024);
  wconv_k<<<dim3(32, 64),  256, 0, stream>>>(W_out,  WoT, 2048, 1024);
  wconv_k<<<dim3(128, 32), 256, 0, stream>>>(W_ff1,  Wf1T, 1024, 4096);
  wconv_k<<<dim3(32, 128), 256, 0, stream>>>(W_ff2,  Wf2T, 4096, 1024);
  // 1. x_norm (bf16)
  rmsnorm_bf_k<<<Mm, 256, 0, stream>>>(x, pre_w, xnbf);
  // 2. conv -> concat[:, 0:D]
  conv_k<<<egrid4, EB, 0, stream>>>(xnbf, conv_w, conv_b, conc);
  // 3. fused gate_pre|a_pre GEMM (N=2048, bf16 out) — 256 blocks, full chip
  bgemm3_k<8><<<dim3(8, 32), 512, 0, stream>>>(xnbf, WgaT, gapre, Mm, 2048, 1024,
      nullptr, nullptr, nullptr, nullptr, nullptr, nullptr);
  // 4-5. chunked scan (gating fused into P1) -> concat[:, D:2D]
  scan_p1<<<512, 256, 0, stream>>>(gapre, xnbf, lam, ubf, carA, carH);
  scan_p2<<<16, 256, 0, stream>>>(carA, carH, initb);
  scan_p3<<<512, 256, 0, stream>>>(gapre, ubf, lam, initb, conc);
  // 6. mixer GEMM (N=1024) -> v7 BN=128, 256 blocks full chip
  bgemm4_k<1 | 16><<<dim3(8, 32), 512, 0, stream>>>(conc, WoT, mixer, Mm, 1024, 2048,
      b_out, nullptr, velocity, x, log_beta, out1);
  // 8. normed = rmsnorm(x_new) (bf16)
  rmsnorm_bf_k<<<Mm, 256, 0, stream>>>(mixer, ffn_w, nrmbf);
  // 9. mid = gelu(normed @ W_ff1 + b_ff1) (bf16) — 512 blocks
  bgemm3_k<1 | 2 | 8><<<dim3(16, 32), 512, 0, stream>>>(nrmbf, Wf1T, midbf, Mm, 4096, 1024,
      b_ff1, nullptr, nullptr, nullptr, nullptr, nullptr);
  // 10. out0 = mid @ W_ff2 + b_ff2 + x_new (fp32, N=1024) -> v7 BN=128
  bgemm4_k<1 | 4><<<dim3(8, 32), 512, 0, stream>>>(midbf, Wf2T, out0, Mm, 1024, 4096,
      b_ff2, mixer, nullptr, nullptr, nullptr, nullptr);
}

// Round 8
// 554.175 us; speedup vs baseline: 1.1130x; 1.0146x over previous
//
#include <hip/hip_runtime.h>

// (B,S,D,K,F) = (4, 2048, 1024, 4, 4096)
static constexpr int Bb = 4;
static constexpr int Ss = 2048;
static constexpr int Dd = 1024;
static constexpr int Ff = 4096;
static constexpr int Mm = Bb * Ss;              // 8192 rows
static constexpr size_t ND = (size_t)Mm * Dd;   // 8388608
static constexpr int CH = 32;                   // scan chunks
static constexpr int CL = Ss / CH;              // chunk length 64

typedef __attribute__((ext_vector_type(8))) short short8;
typedef __attribute__((ext_vector_type(4))) float floatx4;

__device__ __forceinline__ unsigned f2bf(float f) {
  unsigned u = __builtin_bit_cast(unsigned, f);
  return (u + 0x7FFFu + ((u >> 16) & 1u)) >> 16;   // RNE
}
__device__ __forceinline__ float bf2f(unsigned bits) {
  return __builtin_bit_cast(float, bits << 16);
}
__device__ __forceinline__ void gload_lds16(const void* g, void* lds) {
  __builtin_amdgcn_global_load_lds((const __attribute__((address_space(1))) void*)g,
                                   (__attribute__((address_space(3))) void*)lds,
                                   16, 0, 0);
}
// fast sigmoid / tanh-gelu via hw v_exp_f32 + v_rcp_f32 (f32-accurate ~1e-6)
__device__ __forceinline__ float fsig(float x) {
  return __builtin_amdgcn_rcpf(1.0f + __expf(-x));
}
__device__ __forceinline__ float fgelu(float v) {
  float z = 1.5957691216057308f * fmaf(0.044715f * v, v * v, v);
  return v * __builtin_amdgcn_rcpf(1.0f + __expf(-z));
}

// ---------------- weight transpose + fp32->bf16: W[K][N] -> WT[N][K] --------
__global__ __launch_bounds__(256) void wconv_k(const float* __restrict__ W,
                                               unsigned short* __restrict__ WT,
                                               int K, int N) {
  __shared__ float tile[32][33];
  int tx = threadIdx.x & 31, ty = threadIdx.x >> 5;
  int bx = blockIdx.x * 32, by = blockIdx.y * 32;
#pragma unroll
  for (int i = 0; i < 32; i += 8)
    tile[ty + i][tx] = W[(size_t)(by + ty + i) * N + bx + tx];
  __syncthreads();
#pragma unroll
  for (int i = 0; i < 32; i += 8)
    WT[(size_t)(bx + ty + i) * K + by + tx] = (unsigned short)f2bf(tile[tx][ty + i]);
}

// ---------------- RMSNorm: fp32 in, bf16 out --------------------------------
__global__ __launch_bounds__(256) void rmsnorm_bf_k(const float* __restrict__ x,
                                                    const float* __restrict__ w,
                                                    unsigned short* __restrict__ out) {
  int row = blockIdx.x;
  const float4* xr = (const float4*)(x + (size_t)row * Dd);
  int t = threadIdx.x;
  float4 v = xr[t];
  float ss = v.x * v.x + v.y * v.y + v.z * v.z + v.w * v.w;
#pragma unroll
  for (int off = 32; off > 0; off >>= 1) ss += __shfl_down(ss, off, 64);
  __shared__ float sb[4];
  if ((t & 63) == 0) sb[t >> 6] = ss;
  __syncthreads();
  float tot = sb[0] + sb[1] + sb[2] + sb[3];
  float sc = rsqrtf(tot * (1.0f / (float)Dd) + 1e-6f);
  float4 wv = ((const float4*)w)[t];
  unsigned lo = f2bf(v.x * sc * wv.x) | (f2bf(v.y * sc * wv.y) << 16);
  unsigned hi = f2bf(v.z * sc * wv.z) | (f2bf(v.w * sc * wv.w) << 16);
  *(uint2*)(out + (size_t)row * Dd + t * 4) = make_uint2(lo, hi);
}

// ---------------- Causal depthwise conv (bf16 in/out) -> concat[:,0:D] ------
__global__ __launch_bounds__(256) void conv_k(const unsigned short* __restrict__ xn,
                                              const float* __restrict__ kern,
                                              const float* __restrict__ bias,
                                              unsigned short* __restrict__ outC) {
  size_t q = (size_t)blockIdx.x * 256 + threadIdx.x;  // over ND/4
  size_t i = q * 4;
  int d = (int)(i & (Dd - 1));
  int m = (int)(i >> 10);
  int t = m & (Ss - 1);
  float acc[4];
#pragma unroll
  for (int j = 0; j < 4; j++) acc[j] = bias[d + j];
#pragma unroll
  for (int k = 0; k < 4; k++) {
    if (t >= k) {
      uint2 xv = *(const uint2*)(xn + i - (size_t)k * Dd);
      float x0 = bf2f(xv.x & 0xFFFF), x1 = bf2f(xv.x >> 16);
      float x2 = bf2f(xv.y & 0xFFFF), x3 = bf2f(xv.y >> 16);
      acc[0] = fmaf(kern[(d + 0) * 4 + k], x0, acc[0]);
      acc[1] = fmaf(kern[(d + 1) * 4 + k], x1, acc[1]);
      acc[2] = fmaf(kern[(d + 2) * 4 + k], x2, acc[2]);
      acc[3] = fmaf(kern[(d + 3) * 4 + k], x3, acc[3]);
    }
  }
  unsigned lo = f2bf(acc[0]) | (f2bf(acc[1]) << 16);
  unsigned hi = f2bf(acc[2]) | (f2bf(acc[3]) << 16);
  *(uint2*)(outC + (size_t)m * (2 * Dd) + d) = make_uint2(lo, hi);
}

// ---------------- bf16 MFMA GEMM v8: 256x256 8-phase + triple-A ring --------
// v4 skeleton (measured r4/r5: FETCH collapse, 0 conflicts, VGPR=128) with
// the v7 triple-A ring ported over (v7 measured +13% on bgemm4: A lead time
// 3-4 phases -> 12 phases clears ~900cy HBM latency). LDS = 3x32K (A ring) +
// 2x32K (B dbuf) = 160 KiB (HW max, still 1 block/CU).
// Stage map: p0/p1 A(T+2)->a2 | p2/p3 B(T+2)->B0 | p4/p5 A(T+3)->a0 (slot
// freed at p2) | p6/p7 B(T+3)->B1. FIFO: invariant 8 in flight entering each
// iter (A(T+1)x4 + B(T+1)x4); GATE1(p3)=vmcnt(8) completes exactly
// A(T+1)+B(T+1) (consumed p4); GATE2(p7)=vmcnt(8) completes A(T+2)+B(T+2)
// (consumed next p0). vmcnt(0) only final iter. Rotation (a0,a1,a2)<-(a2,a0,a1).
// MODE bits: 1=+bias[col], 2=gelu, 4=+extra (fp32), 8=bf16 out, 16=velocity
template <int MODE>
__global__ __launch_bounds__(512, 2) void bgemm3_k(const unsigned short* __restrict__ A,
                                                   const unsigned short* __restrict__ BT,
                                                   void* __restrict__ Cout,
                                                   int M, int N, int K,
                                                   const float* __restrict__ bias,
                                                   const float* __restrict__ extra,
                                                   const float* __restrict__ vel_in,
                                                   const float* __restrict__ x_in,
                                                   const float* __restrict__ log_beta,
                                                   float* __restrict__ vel_out) {
  __shared__ unsigned short LA[3][256 * 64];   // 96 KiB (triple-A ring)
  __shared__ unsigned short LB[2][256 * 64];   // 64 KiB
  const int tid = threadIdx.x;
  const int wid = tid >> 6, lane = tid & 63;
  const int wm = wid >> 2, wn = wid & 3;       // 2M x 4N wave grid
  const int r = lane & 15, quad = lane >> 4, r7 = lane & 7;

  const int gx = gridDim.x;
  int id = blockIdx.y * gx + blockIdx.x;
  const int nwg = gx * gridDim.y;
  id = (id & 7) * (nwg >> 3) + (id >> 3);
  const int bm = (id / gx) * 256, bn = (id % gx) * 256;
  const int NIT = K >> 7;                      // iterations of 2 K-tiles

  const int lrow = lane >> 3;
  const int sblk = (lane & 7) ^ lrow;          // pre-swizzled 16B block index
  const unsigned short* AsrcB = A  + (size_t)(bm + lrow) * K + sblk * 8;
  const unsigned short* BsrcB = BT + (size_t)(bn + lrow) * K + sblk * 8;

  unsigned short* a0 = &LA[0][0];              // slot of tile T
  unsigned short* a1 = &LA[1][0];              // slot of tile T+1
  unsigned short* a2 = &LA[2][0];              // stage target for T+2
  unsigned short* Bu0 = &LB[0][0];             // B of even tile
  unsigned short* Bu1 = &LB[1][0];             // B of odd tile

  const int aB = wm * 8192 + r * 64;
  const int bB = wn * 4096 + r * 64;
  const int kq0 = (quad ^ r7) * 8;
  const int kq1 = ((4 + quad) ^ r7) * 8;

  floatx4 acc[8][4];
#pragma unroll
  for (int i = 0; i < 8; i++)
#pragma unroll
    for (int j = 0; j < 4; j++) acc[i][j] = (floatx4){0.f, 0.f, 0.f, 0.f};

#define STG_A(dst, k0, h, s)                                                          \
  gload_lds16(AsrcB + (size_t)((h) * 128 + (s) * 64 + wid * 8) * K + (k0),            \
              (void*)((dst) + ((h) * 128 + (s) * 64 + wid * 8) * 64))
#define STG_B(dst, k0, h, s)                                                          \
  gload_lds16(BsrcB + (size_t)((h) * 128 + (s) * 64 + wid * 8) * K + (k0),            \
              (void*)((dst) + ((h) * 128 + (s) * 64 + wid * 8) * 64))
#define RDA(src, il, IH)                                                              \
  aF[il][0] = *(const short8*)((src) + aB + (IH) * 4096 + (il) * 1024 + kq0);         \
  aF[il][1] = *(const short8*)((src) + aB + (IH) * 4096 + (il) * 1024 + kq1)
#define RDB(BF, src, jl, jg)                                                          \
  BF[jl][0] = *(const short8*)((src) + bB + (jg) * 1024 + kq0);                       \
  BF[jl][1] = *(const short8*)((src) + bB + (jg) * 1024 + kq1)
#define MM2(il, jl, BF, IH, JH)                                                       \
  acc[(IH) * 4 + (il)][(JH) * 2 + (jl)] = __builtin_amdgcn_mfma_f32_16x16x32_bf16(    \
      BF[jl][0], aF[il][0], acc[(IH) * 4 + (il)][(JH) * 2 + (jl)], 0, 0, 0);          \
  acc[(IH) * 4 + (il)][(JH) * 2 + (jl)] = __builtin_amdgcn_mfma_f32_16x16x32_bf16(    \
      BF[jl][1], aF[il][1], acc[(IH) * 4 + (il)][(JH) * 2 + (jl)], 0, 0, 0)
#define MQUAD(BF, IH, JH)                                                             \
  MM2(0, 0, BF, IH, JH); MM2(0, 1, BF, IH, JH); MM2(1, 0, BF, IH, JH);                \
  MM2(1, 1, BF, IH, JH); MM2(2, 0, BF, IH, JH); MM2(2, 1, BF, IH, JH);                \
  MM2(3, 0, BF, IH, JH); MM2(3, 1, BF, IH, JH)
#define BAR() __builtin_amdgcn_s_barrier()
#define LGK0()                                                                        \
  asm volatile("s_waitcnt lgkmcnt(0)" ::: "memory");                                  \
  __builtin_amdgcn_sched_barrier(0)
#define PRIO(x) __builtin_amdgcn_s_setprio(x)

  // ---- prologue: A(0)->a0, B(0)->Bu0, A(1)->a1, B(1)->Bu1 (issue order!)
  STG_A(a0, 0, 0, 0); STG_A(a0, 0, 0, 1); STG_A(a0, 0, 1, 0); STG_A(a0, 0, 1, 1);
  STG_B(Bu0, 0, 0, 0); STG_B(Bu0, 0, 0, 1); STG_B(Bu0, 0, 1, 0); STG_B(Bu0, 0, 1, 1);
  STG_A(a1, 64, 0, 0); STG_A(a1, 64, 0, 1); STG_A(a1, 64, 1, 0); STG_A(a1, 64, 1, 1);
  STG_B(Bu1, 64, 0, 0); STG_B(Bu1, 64, 0, 1); STG_B(Bu1, 64, 1, 0); STG_B(Bu1, 64, 1, 1);
  asm volatile("s_waitcnt vmcnt(8)" ::: "memory");
  BAR();
  __builtin_amdgcn_sched_barrier(0);

  for (int it = 0; it < NIT; ++it) {
    const int T = 2 * it;
    const int pf = (it + 1 < NIT);
    const int k2 = (T + 2) << 6, k3 = (T + 3) << 6;
    short8 aF[4][2], b0[2][2], b1[2][2];

    // p0: stage A(T+2)h0 -> a2 ; read A(T)q0 (a0) + B(T)j01 (Bu0); MFMA (0,0)
    if (pf) { STG_A(a2, k2, 0, 0); STG_A(a2, k2, 0, 1); }
    RDA(a0, 0, 0); RDA(a0, 1, 0); RDA(a0, 2, 0); RDA(a0, 3, 0);
    RDB(b0, Bu0, 0, 0); RDB(b0, Bu0, 1, 1);
    BAR(); LGK0();
    PRIO(1); MQUAD(b0, 0, 0); PRIO(0);
    BAR();

    // p1: stage A(T+2)h1 -> a2 ; read B(T)j23; MFMA (0,1)
    if (pf) { STG_A(a2, k2, 1, 0); STG_A(a2, k2, 1, 1); }
    RDB(b1, Bu0, 0, 2); RDB(b1, Bu0, 1, 3);
    BAR(); LGK0();
    PRIO(1); MQUAD(b1, 0, 1); PRIO(0);
    BAR();

    // p2: stage B(T+2)h0 -> Bu0 (B(T) reads done at p1) ; read A(T)q1; MFMA (1,0)
    if (pf) { STG_B(Bu0, k2, 0, 0); STG_B(Bu0, k2, 0, 1); }
    RDA(a0, 0, 1); RDA(a0, 1, 1); RDA(a0, 2, 1); RDA(a0, 3, 1);
    BAR(); LGK0();
    PRIO(1); MQUAD(b0, 1, 0); PRIO(0);
    BAR();

    // p3: stage B(T+2)h1 -> Bu0 ; MFMA (1,1) ; GATE1: complete A(T+1)+B(T+1)
    if (pf) { STG_B(Bu0, k2, 1, 0); STG_B(Bu0, k2, 1, 1); }
    BAR();
    PRIO(1); MQUAD(b1, 1, 1); PRIO(0);
    if (pf) asm volatile("s_waitcnt vmcnt(8)" ::: "memory");
    else    asm volatile("s_waitcnt vmcnt(0)" ::: "memory");
    BAR();
    __builtin_amdgcn_sched_barrier(0);

    // p4: stage A(T+3)h0 -> a0 (A(T) dead after p2+p3 barriers) ;
    //     read A(T+1)q0 (a1) + B(T+1)j01 (Bu1); MFMA (0,0)
    if (pf) { STG_A(a0, k3, 0, 0); STG_A(a0, k3, 0, 1); }
    RDA(a1, 0, 0); RDA(a1, 1, 0); RDA(a1, 2, 0); RDA(a1, 3, 0);
    RDB(b0, Bu1, 0, 0); RDB(b0, Bu1, 1, 1);
    BAR(); LGK0();
    PRIO(1); MQUAD(b0, 0, 0); PRIO(0);
    BAR();

    // p5: stage A(T+3)h1 -> a0 ; read B(T+1)j23; MFMA (0,1)
    if (pf) { STG_A(a0, k3, 1, 0); STG_A(a0, k3, 1, 1); }
    RDB(b1, Bu1, 0, 2); RDB(b1, Bu1, 1, 3);
    BAR(); LGK0();
    PRIO(1); MQUAD(b1, 0, 1); PRIO(0);
    BAR();

    // p6: stage B(T+3)h0 -> Bu1 (B(T+1) reads done at p5) ; read A(T+1)q1; MFMA (1,0)
    if (pf) { STG_B(Bu1, k3, 0, 0); STG_B(Bu1, k3, 0, 1); }
    RDA(a1, 0, 1); RDA(a1, 1, 1); RDA(a1, 2, 1); RDA(a1, 3, 1);
    BAR(); LGK0();
    PRIO(1); MQUAD(b0, 1, 0); PRIO(0);
    BAR();

    // p7: stage B(T+3)h1 -> Bu1 ; MFMA (1,1) ; GATE2: complete A(T+2)+B(T+2)
    if (pf) { STG_B(Bu1, k3, 1, 0); STG_B(Bu1, k3, 1, 1); }
    BAR();
    PRIO(1); MQUAD(b1, 1, 1); PRIO(0);
    if (pf) {
      asm volatile("s_waitcnt vmcnt(8)" ::: "memory");
      BAR();
      __builtin_amdgcn_sched_barrier(0);
    }

    // rotate A ring: new T -> old a2 (holds T+2); new T+1 -> old a0 (T+3)
    unsigned short* tmp = a2; a2 = a1; a1 = a0; a0 = tmp;
  }
#undef STG_A
#undef STG_B
#undef RDA
#undef RDB
#undef MM2
#undef MQUAD

  // acc[i][j][0..3] = C[row = bm+wm*128+i*16+r][col = bn+wn*64+j*16+quad*4 +0..3]
#pragma unroll
  for (int i = 0; i < 8; i++) {
    int rowg = bm + wm * 128 + i * 16 + r;
#pragma unroll
    for (int j = 0; j < 4; j++) {
      int colg = bn + wn * 64 + j * 16 + quad * 4;
      size_t idx = (size_t)rowg * N + colg;
      float v0 = acc[i][j][0], v1 = acc[i][j][1], v2 = acc[i][j][2], v3 = acc[i][j][3];
      if (MODE & 1) {
        float4 bv = *(const float4*)(bias + colg);
        v0 += bv.x; v1 += bv.y; v2 += bv.z; v3 += bv.w;
      }
      if (MODE & 2) {
        v0 = fgelu(v0); v1 = fgelu(v1); v2 = fgelu(v2); v3 = fgelu(v3);
      }
      if (MODE & 4) {
        float4 ev = *(const float4*)(extra + idx);
        v0 += ev.x; v1 += ev.y; v2 += ev.z; v3 += ev.w;
      }
      if (MODE & 16) {
        float4 lb = *(const float4*)(log_beta + colg);
        float4 vi = *(const float4*)(vel_in + idx);
        float4 xi = *(const float4*)(x_in + idx);
        float4 vn;
        vn.x = fmaf(fsig(lb.x), vi.x, v0);
        vn.y = fmaf(fsig(lb.y), vi.y, v1);
        vn.z = fmaf(fsig(lb.z), vi.z, v2);
        vn.w = fmaf(fsig(lb.w), vi.w, v3);
        *(float4*)(vel_out + idx) = vn;
        v0 = xi.x + vn.x; v1 = xi.y + vn.y; v2 = xi.z + vn.z; v3 = xi.w + vn.w;
      }
      if (MODE & 8) {
        uint2 pk;
        pk.x = f2bf(v0) | (f2bf(v1) << 16);
        pk.y = f2bf(v2) | (f2bf(v3) << 16);
        *(uint2*)((unsigned short*)Cout + idx) = pk;
      } else {
        float4 o; o.x = v0; o.y = v1; o.z = v2; o.w = v3;
        *(float4*)((float*)Cout + idx) = o;
      }
    }
  }
}

// ---------------- bf16 MFMA GEMM v7: BN=128, v5 8-phase + triple-A ring ------
// (unchanged from round 7 -- measured: FF2 106->94us, MfmaUtil 25->29%)
template <int MODE>
__global__ __launch_bounds__(512, 2) void bgemm4_k(const unsigned short* __restrict__ A,
                                                   const unsigned short* __restrict__ BT,
                                                   void* __restrict__ Cout,
                                                   int M, int N, int K,
                                                   const float* __restrict__ bias,
                                                   const float* __restrict__ extra,
                                                   const float* __restrict__ vel_in,
                                                   const float* __restrict__ x_in,
                                                   const float* __restrict__ log_beta,
                                                   float* __restrict__ vel_out) {
  __shared__ unsigned short LA[3][256 * 64];   // 96 KiB (triple-A ring)
  __shared__ unsigned short LB[2][128 * 64];   // 32 KiB
  const int tid = threadIdx.x;
  const int wid = tid >> 6, lane = tid & 63;
  const int wm = wid >> 1, wn = wid & 1;       // 4M x 2N wave grid
  const int r = lane & 15, quad = lane >> 4, r7 = lane & 7;

  const int gx = gridDim.x;
  int id = blockIdx.y * gx + blockIdx.x;
  const int nwg = gx * gridDim.y;
  id = (id & 7) * (nwg >> 3) + (id >> 3);
  const int bm = (id / gx) * 256, bn = (id % gx) * 128;
  const int NIT = K >> 7;

  const int lrow = lane >> 3;
  const int sblk = (lane & 7) ^ lrow;
  const unsigned short* AsrcB = A  + (size_t)(bm + lrow) * K + sblk * 8;
  const unsigned short* BsrcB = BT + (size_t)(bn + lrow) * K + sblk * 8;

  unsigned short* a0 = &LA[0][0];              // slot of tile T
  unsigned short* a1 = &LA[1][0];              // slot of tile T+1
  unsigned short* a2 = &LA[2][0];              // stage target for T+2
  unsigned short* B0 = &LB[0][0];
  unsigned short* B1 = &LB[1][0];

  const int aB = wm * 4096 + r * 64;           // wm*64 rows
  const int bB = wn * 4096 + r * 64;           // wn*64 rows
  const int kq0 = (quad ^ r7) * 8;
  const int kq1 = ((4 + quad) ^ r7) * 8;

  floatx4 acc[4][4];
#pragma unroll
  for (int i = 0; i < 4; i++)
#pragma unroll
    for (int j = 0; j < 4; j++) acc[i][j] = (floatx4){0.f, 0.f, 0.f, 0.f};

#define STG_A7(dst, k0, h, s)                                                         \
  gload_lds16(AsrcB + (size_t)((h) * 128 + (s) * 64 + wid * 8) * K + (k0),            \
              (void*)((dst) + ((h) * 128 + (s) * 64 + wid * 8) * 64))
#define STG_B7(dst, k0, s)                                                            \
  gload_lds16(BsrcB + (size_t)((s) * 64 + wid * 8) * K + (k0),                        \
              (void*)((dst) + ((s) * 64 + wid * 8) * 64))
#define RDA7(src, IH)                                                                 \
  aF[0][0] = *(const short8*)((src) + aB + (IH) * 2048 + kq0);                        \
  aF[0][1] = *(const short8*)((src) + aB + (IH) * 2048 + kq1);                        \
  aF[1][0] = *(const short8*)((src) + aB + (IH) * 2048 + 1024 + kq0);                 \
  aF[1][1] = *(const short8*)((src) + aB + (IH) * 2048 + 1024 + kq1)
#define RDB7(BF, src, JH)                                                             \
  BF[0][0] = *(const short8*)((src) + bB + (JH) * 2048 + kq0);                        \
  BF[0][1] = *(const short8*)((src) + bB + (JH) * 2048 + kq1);                        \
  BF[1][0] = *(const short8*)((src) + bB + (JH) * 2048 + 1024 + kq0);                 \
  BF[1][1] = *(const short8*)((src) + bB + (JH) * 2048 + 1024 + kq1)
#define MM27(il, jl, BF, IH, JH)                                                      \
  acc[(IH) * 2 + (il)][(JH) * 2 + (jl)] = __builtin_amdgcn_mfma_f32_16x16x32_bf16(    \
      BF[jl][0], aF[il][0], acc[(IH) * 2 + (il)][(JH) * 2 + (jl)], 0, 0, 0);          \
  acc[(IH) * 2 + (il)][(JH) * 2 + (jl)] = __builtin_amdgcn_mfma_f32_16x16x32_bf16(    \
      BF[jl][1], aF[il][1], acc[(IH) * 2 + (il)][(JH) * 2 + (jl)], 0, 0, 0)
#define MQ7(BF, IH, JH)                                                               \
  MM27(0, 0, BF, IH, JH); MM27(0, 1, BF, IH, JH);                                     \
  MM27(1, 0, BF, IH, JH); MM27(1, 1, BF, IH, JH)

  // ---- prologue: A(0)->a0, B(0)->B0, A(1)->a1, B(1)->B1 (issue order!)
  STG_A7(a0, 0, 0, 0); STG_A7(a0, 0, 0, 1); STG_A7(a0, 0, 1, 0); STG_A7(a0, 0, 1, 1);
  STG_B7(B0, 0, 0); STG_B7(B0, 0, 1);
  STG_A7(a1, 64, 0, 0); STG_A7(a1, 64, 0, 1); STG_A7(a1, 64, 1, 0); STG_A7(a1, 64, 1, 1);
  STG_B7(B1, 64, 0); STG_B7(B1, 64, 1);
  asm volatile("s_waitcnt vmcnt(6)" ::: "memory");
  BAR();
  __builtin_amdgcn_sched_barrier(0);

  for (int it = 0; it < NIT; ++it) {
    const int T = 2 * it;
    const int pf = (it + 1 < NIT);
    const int k2 = (T + 2) << 6, k3 = (T + 3) << 6;
    short8 aF[2][2], b0f[2][2], b1f[2][2];

    // p0: stage A(T+2)h0 -> a2 ; read A(T)q0 (a0) + B(T)j01 (B0); MFMA (0,0)
    if (pf) { STG_A7(a2, k2, 0, 0); STG_A7(a2, k2, 0, 1); }
    RDA7(a0, 0); RDB7(b0f, B0, 0);
    BAR(); LGK0();
    PRIO(1); MQ7(b0f, 0, 0); PRIO(0);
    BAR();

    // p1: stage A(T+2)h1 -> a2 ; read B(T)j23; MFMA (0,1)
    if (pf) { STG_A7(a2, k2, 1, 0); STG_A7(a2, k2, 1, 1); }
    RDB7(b1f, B0, 1);
    BAR(); LGK0();
    PRIO(1); MQ7(b1f, 0, 1); PRIO(0);
    BAR();

    // p2: stage B(T+2)s0 -> B0 (B(T) reads done at p1) ; read A(T)q1; MFMA (1,0)
    if (pf) STG_B7(B0, k2, 0);
    RDA7(a0, 1);
    BAR(); LGK0();
    PRIO(1); MQ7(b0f, 1, 0); PRIO(0);
    BAR();

    // p3: stage B(T+2)s1 -> B0 ; MFMA (1,1) ; GATE1: complete A(T+1)+B(T+1)
    if (pf) STG_B7(B0, k2, 1);
    BAR();
    PRIO(1); MQ7(b1f, 1, 1); PRIO(0);
    if (pf) asm volatile("s_waitcnt vmcnt(6)" ::: "memory");
    else    asm volatile("s_waitcnt vmcnt(0)" ::: "memory");
    BAR();
    __builtin_amdgcn_sched_barrier(0);

    // p4: stage A(T+3)h0 -> a0 (A(T) dead after p2+p3 barrier) ;
    //     read A(T+1)q0 (a1) + B(T+1)j01 (B1); MFMA (0,0)
    if (pf) { STG_A7(a0, k3, 0, 0); STG_A7(a0, k3, 0, 1); }
    RDA7(a1, 0); RDB7(b0f, B1, 0);
    BAR(); LGK0();
    PRIO(1); MQ7(b0f, 0, 0); PRIO(0);
    BAR();

    // p5: stage A(T+3)h1 -> a0 ; read B(T+1)j23; MFMA (0,1)
    if (pf) { STG_A7(a0, k3, 1, 0); STG_A7(a0, k3, 1, 1); }
    RDB7(b1f, B1, 1);
    BAR(); LGK0();
    PRIO(1); MQ7(b1f, 0, 1); PRIO(0);
    BAR();

    // p6: stage B(T+3)s0 -> B1 (B(T+1) reads done at p5) ; read A(T+1)q1; MFMA (1,0)
    if (pf) STG_B7(B1, k3, 0);
    RDA7(a1, 1);
    BAR(); LGK0();
    PRIO(1); MQ7(b0f, 1, 0); PRIO(0);
    BAR();

    // p7: stage B(T+3)s1 -> B1 ; MFMA (1,1) ; GATE2: complete A(T+2)+B(T+2)
    if (pf) STG_B7(B1, k3, 1);
    BAR();
    PRIO(1); MQ7(b1f, 1, 1); PRIO(0);
    if (pf) {
      asm volatile("s_waitcnt vmcnt(6)" ::: "memory");
      BAR();
      __builtin_amdgcn_sched_barrier(0);
    }

    // rotate A ring: new T -> old a2 (holds T+2); new T+1 -> old a0 (T+3)
    unsigned short* tmp = a2; a2 = a1; a1 = a0; a0 = tmp;
  }
#undef STG_A7
#undef STG_B7
#undef RDA7
#undef RDB7
#undef MM27
#undef MQ7
#undef BAR
#undef LGK0
#undef PRIO

  // acc[i][j][0..3] = C[row = bm+wm*64+i*16+r][col = bn+wn*64+j*16+quad*4 +0..3]
#pragma unroll
  for (int i = 0; i < 4; i++) {
    int rowg = bm + wm * 64 + i * 16 + r;
#pragma unroll
    for (int j = 0; j < 4; j++) {
      int colg = bn + wn * 64 + j * 16 + quad * 4;
      size_t idx = (size_t)rowg * N + colg;
      float v0 = acc[i][j][0], v1 = acc[i][j][1], v2 = acc[i][j][2], v3 = acc[i][j][3];
      if (MODE & 1) {
        float4 bv = *(const float4*)(bias + colg);
        v0 += bv.x; v1 += bv.y; v2 += bv.z; v3 += bv.w;
      }
      if (MODE & 2) {
        v0 = fgelu(v0); v1 = fgelu(v1); v2 = fgelu(v2); v3 = fgelu(v3);
      }
      if (MODE & 4) {
        float4 ev = *(const float4*)(extra + idx);
        v0 += ev.x; v1 += ev.y; v2 += ev.z; v3 += ev.w;
      }
      if (MODE & 16) {
        float4 lb = *(const float4*)(log_beta + colg);
        float4 vi = *(const float4*)(vel_in + idx);
        float4 xi = *(const float4*)(x_in + idx);
        float4 vn;
        vn.x = fmaf(fsig(lb.x), vi.x, v0);
        vn.y = fmaf(fsig(lb.y), vi.y, v1);
        vn.z = fmaf(fsig(lb.z), vi.z, v2);
        vn.w = fmaf(fsig(lb.w), vi.w, v3);
        *(float4*)(vel_out + idx) = vn;
        v0 = xi.x + vn.x; v1 = xi.y + vn.y; v2 = xi.z + vn.z; v3 = xi.w + vn.w;
      }
      if (MODE & 8) {
        uint2 pk;
        pk.x = f2bf(v0) | (f2bf(v1) << 16);
        pk.y = f2bf(v2) | (f2bf(v3) << 16);
        *(uint2*)((unsigned short*)Cout + idx) = pk;
      } else {
        float4 o; o.x = v0; o.y = v1; o.z = v2; o.w = v3;
        *(float4*)((float*)Cout + idx) = o;
      }
    }
  }
}

// ---------------- scan phase 1: gating + per-chunk (A, h_local) -------------
__global__ __launch_bounds__(256) void scan_p1(const unsigned short* __restrict__ gapre,
                                               const unsigned short* __restrict__ xn,
                                               const float* __restrict__ lam,
                                               unsigned short* __restrict__ ub,
                                               float* __restrict__ carryA,
                                               float* __restrict__ carryH) {
  int g = blockIdx.x * 256 + threadIdx.x;    // 0..131071
  int e = g & (Dd - 1);
  int bc = g >> 10;
  int b = bc & 3;
  int c = bc >> 2;
  float l = lam[e];
  float sp = fmaxf(l, 0.0f) + log1pf(__expf(-fabsf(l)));
  float m8sp = -8.0f * sp;
  size_t m0 = (size_t)b * Ss + (size_t)c * CL;
  float A = 1.0f, h = 0.0f;
#pragma unroll 4
  for (int t = 0; t < CL; t++) {
    size_t m = m0 + t;
    float gp = bf2f(gapre[m * 2048 + e]);
    float ap = bf2f(gapre[m * 2048 + 1024 + e]);
    float xv = bf2f(xn[m * Dd + e]);
    float a = __expf(m8sp * fsig(ap));
    float u = sqrtf(fmaxf(1.0f - a * a, 0.0f)) * fsig(gp) * xv;
    ub[m * Dd + e] = (unsigned short)f2bf(u);
    A *= a;
    h = fmaf(a, h, u);
  }
  carryA[c * 4096 + b * 1024 + e] = A;
  carryH[c * 4096 + b * 1024 + e] = h;
}

// ---------------- scan phase 2: scan carries -> per-chunk init state --------
__global__ __launch_bounds__(256) void scan_p2(const float* __restrict__ carryA,
                                               const float* __restrict__ carryH,
                                               float* __restrict__ init) {
  int ch = blockIdx.x * 256 + threadIdx.x;   // 0..4095
  float H = 0.0f;
#pragma unroll
  for (int c = 0; c < CH; c++) {
    init[c * 4096 + ch] = H;
    H = fmaf(carryA[c * 4096 + ch], H, carryH[c * 4096 + ch]);
  }
}

// ---------------- scan phase 3: rescan chunk with init -> concat[:,D:2D] ----
__global__ __launch_bounds__(256) void scan_p3(const unsigned short* __restrict__ gapre,
                                               const unsigned short* __restrict__ ub,
                                               const float* __restrict__ lam,
                                               const float* __restrict__ init,
                                               unsigned short* __restrict__ outC) {
  int g = blockIdx.x * 256 + threadIdx.x;
  int e = g & (Dd - 1);
  int bc = g >> 10;
  int b = bc & 3;
  int c = bc >> 2;
  float l = lam[e];
  float sp = fmaxf(l, 0.0f) + log1pf(__expf(-fabsf(l)));
  float m8sp = -8.0f * sp;
  size_t m0 = (size_t)b * Ss + (size_t)c * CL;
  float h = init[c * 4096 + b * 1024 + e];
#pragma unroll 4
  for (int t = 0; t < CL; t++) {
    size_t m = m0 + t;
    float ap = bf2f(gapre[m * 2048 + 1024 + e]);
    float a = __expf(m8sp * fsig(ap));
    float u = bf2f(ub[m * Dd + e]);
    h = fmaf(a, h, u);
    outC[m * (2 * Dd) + Dd + e] = (unsigned short)f2bf(h);
  }
}

extern "C" void kernel_launch(void* const* d_in, const int* in_sizes, int n_in,
                              void* d_out, int out_size, void* d_ws, size_t ws_size,
                              hipStream_t stream) {
  const float* x        = (const float*)d_in[0];
  const float* velocity = (const float*)d_in[1];
  const float* pre_w    = (const float*)d_in[2];
  const float* conv_w   = (const float*)d_in[3];
  const float* conv_b   = (const float*)d_in[4];
  const float* W_gate   = (const float*)d_in[5];
  const float* W_a      = (const float*)d_in[6];
  const float* lam      = (const float*)d_in[7];
  const float* W_out    = (const float*)d_in[8];
  const float* b_out    = (const float*)d_in[9];
  const float* log_beta = (const float*)d_in[10];
  const float* ffn_w    = (const float*)d_in[11];
  const float* W_ff1    = (const float*)d_in[12];
  const float* b_ff1    = (const float*)d_in[13];
  const float* W_ff2    = (const float*)d_in[14];
  const float* b_ff2    = (const float*)d_in[15];

  float* out0 = (float*)d_out;
  float* out1 = out0 + ND;

  // ---- workspace (byte offsets), lifetime-aliased; peak 152 MB ----
  const size_t MB = 1024 * 1024;
  char* ws = (char*)d_ws;
  unsigned short* WgaT  = (unsigned short*)ws;               // 2048x1024 [0,4) (gate|a)
  unsigned short* WoT   = WgaT + (size_t)2 * 1024 * 1024;    // [4,8)
  unsigned short* Wf1T  = WoT + (size_t)2 * 1024 * 1024;     // [8,16)
  unsigned short* Wf2T  = Wf1T + (size_t)4 * 1024 * 1024;    // [16,24)
  float*          mixer = (float*)(ws + 24 * MB);            // 32 MB [24,56) — x_new
  float*          carA  = (float*)(ws + 24 * MB);            // overlay (pre-step-6)
  float*          carH  = (float*)(ws + 24 * MB + 512 * 1024);
  float*          initb = (float*)(ws + 25 * MB);
  unsigned short* conc  = (unsigned short*)(ws + 56 * MB);   // 32 MB [56,88)
  unsigned short* gapre = (unsigned short*)(ws + 88 * MB);   // 32 MB [88,120)
  unsigned short* xnbf  = (unsigned short*)(ws + 120 * MB);  // 16 MB [120,136)
  unsigned short* ubf   = (unsigned short*)(ws + 136 * MB);  // 16 MB [136,152)
  unsigned short* midbf = (unsigned short*)(ws + 88 * MB);   // 64 MB overlay [88,152)
  unsigned short* nrmbf = (unsigned short*)(ws + 56 * MB);   // overlay conc

  const int EB = 256;
  const int egrid4 = (int)(ND / 4 / EB);

  // 0. weight transpose + bf16 convert (gate|a combined, contiguous)
  wconv_k<<<dim3(32, 32),  256, 0, stream>>>(W_gate, WgaT, 1024, 1024);
  wconv_k<<<dim3(32, 32),  256, 0, stream>>>(W_a,    WgaT + (size_t)1024 * 1024, 1024, 1024);
  wconv_k<<<dim3(32, 64),  256, 0, stream>>>(W_out,  WoT, 2048, 1024);
  wconv_k<<<dim3(128, 32), 256, 0, stream>>>(W_ff1,  Wf1T, 1024, 4096);
  wconv_k<<<dim3(32, 128), 256, 0, stream>>>(W_ff2,  Wf2T, 4096, 1024);
  // 1. x_norm (bf16)
  rmsnorm_bf_k<<<Mm, 256, 0, stream>>>(x, pre_w, xnbf);
  // 2. conv -> concat[:, 0:D]
  conv_k<<<egrid4, EB, 0, stream>>>(xnbf, conv_w, conv_b, conc);
  // 3. fused gate_pre|a_pre GEMM (N=2048, bf16 out) — v8 triple-A, full chip
  bgemm3_k<8><<<dim3(8, 32), 512, 0, stream>>>(xnbf, WgaT, gapre, Mm, 2048, 1024,
      nullptr, nullptr, nullptr, nullptr, nullptr, nullptr);
  // 4-5. chunked scan (gating fused into P1) -> concat[:, D:2D]
  scan_p1<<<512, 256, 0, stream>>>(gapre, xnbf, lam, ubf, carA, carH);
  scan_p2<<<16, 256, 0, stream>>>(carA, carH, initb);
  scan_p3<<<512, 256, 0, stream>>>(gapre, ubf, lam, initb, conc);
  // 6. mixer GEMM (N=1024) -> v7 BN=128, 256 blocks full chip
  bgemm4_k<1 | 16><<<dim3(8, 32), 512, 0, stream>>>(conc, WoT, mixer, Mm, 1024, 2048,
      b_out, nullptr, velocity, x, log_beta, out1);
  // 8. normed = rmsnorm(x_new) (bf16)
  rmsnorm_bf_k<<<Mm, 256, 0, stream>>>(mixer, ffn_w, nrmbf);
  // 9. mid = gelu(normed @ W_ff1 + b_ff1) (bf16) — v8 triple-A, 512 blocks
  bgemm3_k<1 | 2 | 8><<<dim3(16, 32), 512, 0, stream>>>(nrmbf, Wf1T, midbf, Mm, 4096, 1024,
      b_ff1, nullptr, nullptr, nullptr, nullptr, nullptr);
  // 10. out0 = mid @ W_ff2 + b_ff2 + x_new (fp32, N=1024) -> v7 BN=128
  bgemm4_k<1 | 4><<<dim3(8, 32), 512, 0, stream>>>(midbf, Wf2T, out0, Mm, 1024, 4096,
      b_ff2, mixer, nullptr, nullptr, nullptr, nullptr);
}